// Round 4
// baseline (25254.141 us; speedup 1.0000x reference)
//
#include <hip/hip_runtime.h>
#include <hip/hip_bf16.h>

// Sizes from the reference
#define T_   4096
#define E_   8
#define NCON 208   // consumer blocks (total grid = 32 + 8 + NCON = 248)

typedef unsigned long long ull;

__device__ __forceinline__ float sigm(float x)  { return 1.0f / (1.0f + __expf(-x)); }
__device__ __forceinline__ float tanh_(float x) { return 1.0f - 2.0f / (__expf(2.0f * x) + 1.0f); }

__device__ __forceinline__ ull aload64(const ull* p) {
  return __hip_atomic_load(p, __ATOMIC_RELAXED, __HIP_MEMORY_SCOPE_AGENT);
}
__device__ __forceinline__ int aload32(const int* p) {
  return __hip_atomic_load(p, __ATOMIC_RELAXED, __HIP_MEMORY_SCOPE_AGENT);
}
__device__ __forceinline__ float aloadf(const float* p) {
  return __hip_atomic_load(p, __ATOMIC_RELAXED, __HIP_MEMORY_SCOPE_AGENT);
}
// embed 3-bit generation tag in low mantissa bits (error <= 7 ulp)
__device__ __forceinline__ float tagf(float h, unsigned g) {
  return __uint_as_float((__float_as_uint(h) & ~7u) | g);
}
__device__ __forceinline__ float u2f(unsigned u) { return __uint_as_float(u); }
// barrier draining LDS (lgkm) but not vector memory
__device__ __forceinline__ void lbar() {
  asm volatile("s_waitcnt lgkmcnt(0)\n\ts_barrier" ::: "memory");
}

#define FMA_8(ACC, W, VA, VB)                                   \
  ACC[0] = fmaf((W), (VA).x, ACC[0]); ACC[1] = fmaf((W), (VA).y, ACC[1]); \
  ACC[2] = fmaf((W), (VA).z, ACC[2]); ACC[3] = fmaf((W), (VA).w, ACC[3]); \
  ACC[4] = fmaf((W), (VB).x, ACC[4]); ACC[5] = fmaf((W), (VB).y, ACC[5]); \
  ACC[6] = fmaf((W), (VB).z, ACC[6]); ACC[7] = fmaf((W), (VB).w, ACC[7]);

// ---------------------------------------------------------------------------
// initK: K-major packed weight copies + zero ring / flags.
// Packing (unchanged): packed col c' = wg*32 + r5, r5 = gate*8 + jl,
// global col = gate*256 + wg*8 + jl.
// ---------------------------------------------------------------------------
__global__ void initK(const float* __restrict__ Wih_p0, const float* __restrict__ Whh_p0,
                      const float* __restrict__ Wih_p1, const float* __restrict__ Whh_p1,
                      const float* __restrict__ Wih_c0, const float* __restrict__ Whh_c0,
                      const float* __restrict__ Wih_c1, const float* __restrict__ Whh_c1,
                      const float* __restrict__ Wih_o,
                      float* wt_p0, float* wt_p1, float* wt_c0, float* wt_c1,
                      float* wt_o1, float* wt_o2, int* zbase) {
  const int NW = 458752 + 524288 + 131072 + 131072 + 131072 + 98304;
  // zero: ringM (8*4096 = 32768) + flagsM (1024) + flagsBC (65536) + flagC (16384)
  const int NZ = 32768 + 1024 + 65536 + 16384;
  const int NTOT = NW + NZ;
  const int gsz = gridDim.x * blockDim.x;
  for (int i = blockIdx.x * blockDim.x + threadIdx.x; i < NTOT; i += gsz) {
    int idx = i;
    if (idx < 458752) { int k = idx >> 10, c = idx & 1023;
      int wg = c >> 5, r5 = c & 31, gate = r5 >> 3, jl = r5 & 7;
      int col = gate * 256 + wg * 8 + jl;
      wt_p0[idx] = (k < 192) ? Wih_p0[col * 192 + k] : Whh_p0[col * 256 + (k - 192)]; continue; }
    idx -= 458752;
    if (idx < 524288) { int k = idx >> 10, c = idx & 1023;
      int wg = c >> 5, r5 = c & 31, gate = r5 >> 3, jl = r5 & 7;
      int col = gate * 256 + wg * 8 + jl;
      wt_p1[idx] = (k < 256) ? Wih_p1[col * 256 + k] : Whh_p1[col * 256 + (k - 256)]; continue; }
    idx -= 524288;
    if (idx < 131072) { int k = idx >> 9, r = idx & 511;
      wt_c0[idx] = (k < 128) ? Wih_c0[r * 128 + k] : Whh_c0[r * 128 + (k - 128)]; continue; }
    idx -= 131072;
    if (idx < 131072) { int k = idx >> 9, r = idx & 511;
      wt_c1[idx] = (k < 128) ? Wih_c1[r * 128 + k] : Whh_c1[r * 128 + (k - 128)]; continue; }
    idx -= 131072;
    if (idx < 131072) { int k = idx >> 9, r = idx & 511;
      wt_o1[idx] = Wih_o[r * 448 + k]; continue; }
    idx -= 131072;
    if (idx < 98304) { int k = idx >> 9, r = idx & 511;
      wt_o2[idx] = Wih_o[r * 448 + 256 + k]; continue; }
    idx -= 98304;
    zbase[idx] = 0;
  }
}

// ---------------------------------------------------------------------------
// opre2K: parallel over t. opre2[t][e][512] = Wih_o[:,256:448] @ x(t,e)  (bf16)
// ---------------------------------------------------------------------------
__global__ void opre2K(const float* __restrict__ feat, const float* __restrict__ wt_o2,
                       __hip_bfloat16* __restrict__ opre2) {
  __shared__ float xb[192 * 8];
  const int t = blockIdx.x, tid = threadIdx.x;
  const float* ft = feat + (size_t)t * 640;
  for (int idx = tid; idx < 192 * 8; idx += 256) {
    int k = idx >> 3, e = idx & 7;
    xb[idx] = (k < 128) ? ft[k] : ft[128 + e * 64 + (k - 128)];
  }
  __syncthreads();
  const int r = tid;
  float A0[8] = {0,0,0,0,0,0,0,0};
  float A1[8] = {0,0,0,0,0,0,0,0};
  const float4* x4 = (const float4*)xb;
  #pragma unroll 2
  for (int k = 0; k < 192; ++k) {
    float w0 = wt_o2[k * 512 + r];
    float w1 = wt_o2[k * 512 + 256 + r];
    float4 a = x4[k * 2], b = x4[k * 2 + 1];
    FMA_8(A0, w0, a, b);
    FMA_8(A1, w1, a, b);
  }
  #pragma unroll
  for (int e = 0; e < 8; ++e) {
    opre2[((size_t)t * 8 + e) * 512 + r]       = __float2bfloat16(A0[e]);
    opre2[((size_t)t * 8 + e) * 512 + 256 + r] = __float2bfloat16(A1[e]);
  }
}

// ---------------------------------------------------------------------------
// comm cell (unchanged math)
// ---------------------------------------------------------------------------
__device__ __forceinline__ void comm_cell(
    const float* __restrict__ wt, const float* __restrict__ bias,
    const float* xin, float* hL, float* cL, float* glb, float* hout,
    float alpha, int tid) {
  const int r = tid;
  float A0[8] = {0,0,0,0,0,0,0,0};
  float A1[8] = {0,0,0,0,0,0,0,0};
  const float4* x4 = (const float4*)xin;
  #pragma unroll 2
  for (int k = 0; k < 128; ++k) {
    float w0 = wt[k * 512 + r];
    float w1 = wt[k * 512 + 256 + r];
    float4 a = x4[k * 2], b = x4[k * 2 + 1];
    FMA_8(A0, w0, a, b);
    FMA_8(A1, w1, a, b);
  }
  const float4* h4 = (const float4*)hL;
  #pragma unroll 2
  for (int k = 0; k < 128; ++k) {
    float w0 = wt[(128 + k) * 512 + r];
    float w1 = wt[(128 + k) * 512 + 256 + r];
    float4 a = h4[k * 2], b = h4[k * 2 + 1];
    FMA_8(A0, w0, a, b);
    FMA_8(A1, w1, a, b);
  }
  {
    float4* g4 = (float4*)glb;
    g4[r * 2]             = make_float4(A0[0], A0[1], A0[2], A0[3]);
    g4[r * 2 + 1]         = make_float4(A0[4], A0[5], A0[6], A0[7]);
    g4[(256 + r) * 2]     = make_float4(A1[0], A1[1], A1[2], A1[3]);
    g4[(256 + r) * 2 + 1] = make_float4(A1[4], A1[5], A1[6], A1[7]);
  }
  __syncthreads();
  for (int idx = tid; idx < 1024; idx += 256) {
    int jj = idx >> 3, tt = idx & 7;
    float gi = glb[jj * 8 + tt]         + bias[jj];
    float gf = glb[(128 + jj) * 8 + tt] + bias[128 + jj];
    float gg = glb[(256 + jj) * 8 + tt] + bias[256 + jj];
    float go = glb[(384 + jj) * 8 + tt] + bias[384 + jj];
    float cold = cL[idx], hold = hL[idx];
    float c2 = sigm(gf) * cold + sigm(gi) * tanh_(gg);
    float h2 = sigm(go) * tanh_(c2);
    float hb = fmaf(alpha, h2 - hold, hold);
    float cb = fmaf(alpha, c2 - cold, cold);
    hL[idx] = hb; cL[idx] = cb;
    if (hout) hout[idx] = hb;
  }
  __syncthreads();
}

// ---------------------------------------------------------------------------
// MEGA kernel: 248 blocks, 256 thr, 161792 B LDS => 1 block/CU => all 248
// resident simultaneously.
//   blocks 0-31 : MERGED layer0+layer1. Block wg holds 32-col slices of BOTH
//     layers. Per iter t: computes h0(t) (layer0) and h1(t-1) (layer1) —
//     both consume h0(t-1), which is in LDS. Publishes both slices (tagged
//     floats) into ONE ring slot with ONE flag => one all-to-all per step.
//     wave0: reduce0+cell0+publish h0 | wave1: reduce1+cell1+publish h1+
//     h1all+flag | wave2: polls the 31 remote flags. No back-pressure
//     anywhere (h1all/opre1 are full-size, consumers can't stall us).
//   blocks 32-39: phaseC per-e output LSTM (unchanged)
//   blocks 40-  : consumers: fused fc+comm per 8-t chunk (flagsBC-gated)
// flagsBC published by wave1 once per 8 h1-steps with a wave-local vmcnt(0)
// ack (orders h1all). The per-step ring flag is un-acked; tags protect.
// ---------------------------------------------------------------------------
__launch_bounds__(256, 1)
__global__ void megaK(const float* __restrict__ feat,
                      const float* __restrict__ pre_h0, const float* __restrict__ pre_c0,
                      const float* __restrict__ wt_p0, const float* __restrict__ wt_p1,
                      const float* __restrict__ b_p0, const float* __restrict__ b_p1,
                      float* __restrict__ ringM, int* __restrict__ flagsM,
                      float* __restrict__ h1all, int* __restrict__ flagsBC,
                      const float* __restrict__ Wfc, const float* __restrict__ bfc,
                      const float* __restrict__ wt_c0, const float* __restrict__ wt_c1,
                      const float* __restrict__ b_c0, const float* __restrict__ b_c1,
                      const float* __restrict__ wt_o1, const float* __restrict__ b_o,
                      float* __restrict__ opre1, int* __restrict__ flagC,
                      const __hip_bfloat16* __restrict__ opre2,
                      const float* __restrict__ Whh_o, const float* __restrict__ out_h0,
                      const float* __restrict__ out_c0, float* __restrict__ oh_g) {
  __shared__ float lds[40448];   // 161,792 B
  const int wg = blockIdx.x, tid = threadIdx.x;

  if (wg < 32) {
    // ==================== MERGED layer0 + layer1 (32 blocks) ====================
    float* wl0  = lds;            // 14336: layer0 weights [k][32], k<448
    float* wl1  = lds + 14336;    // 16384: layer1 weights [k][32], k<512
    float* xbuf = lds + 30720;    // 1536
    float* h0sf = lds + 32256;    // 2048: h0(t-1) [k][e]
    float* h1sf = lds + 34304;    // 2048: h1(t-2) [k][e]
    float* gl0  = lds + 36352;    // 2048 partials layer0
    float* gl1  = lds + 38400;    // 2048 partials layer1
    const int r5 = tid & 31, kq = tid >> 5;
    for (int idx = tid; idx < 14336; idx += 256)
      wl0[idx] = wt_p0[(size_t)(idx >> 5) * 1024 + wg * 32 + (idx & 31)];
    for (int idx = tid; idx < 16384; idx += 256)
      wl1[idx] = wt_p1[(size_t)(idx >> 5) * 1024 + wg * 32 + (idx & 31)];
    float creg = 0.f, bi = 0.f, bff = 0.f, bgg = 0.f, bo = 0.f;
    if (tid < 64) {
      const int jl = tid >> 3, e = tid & 7, j = wg * 8 + jl;
      creg = pre_c0[(e * 2 + 0) * 256 + j];
      bi = b_p0[j]; bff = b_p0[256 + j]; bgg = b_p0[512 + j]; bo = b_p0[768 + j];
    } else if (tid < 128) {
      const int l = tid - 64, jl = l >> 3, e = l & 7, j = wg * 8 + jl;
      creg = pre_c0[(e * 2 + 1) * 256 + j];
      bi = b_p1[j]; bff = b_p1[256 + j]; bgg = b_p1[512 + j]; bo = b_p1[768 + j];
    }
    for (int idx = tid; idx < 2048; idx += 256) {
      const int k = idx >> 3, e = idx & 7;
      h0sf[idx] = pre_h0[(e * 2 + 0) * 256 + k];
      h1sf[idx] = pre_h0[(e * 2 + 1) * 256 + k];
    }
    for (int idx = tid; idx < 1536; idx += 256) {
      const int k = idx >> 3, e = idx & 7;
      xbuf[idx] = (k < 128) ? feat[k] : feat[128 + e * 64 + (k - 128)];
    }
    __syncthreads();
    const bool own = ((tid >> 3) == wg);
    float Ax[8] = {0,0,0,0,0,0,0,0};
    {                                              // prologue x-part for t=0
      const float4* x4 = (const float4*)xbuf;
      #pragma unroll
      for (int k = kq * 24; k < kq * 24 + 24; ++k) {
        float w = wl0[k * 32 + r5];
        float4 a = x4[k * 2], b = x4[k * 2 + 1];
        FMA_8(Ax, w, a, b);
      }
    }
    for (int t = 0; t < T_; ++t) {
      float px[6];
      if (t + 1 < T_) {
        const float* ft1 = feat + (size_t)(t + 1) * 640;
        #pragma unroll
        for (int i = 0; i < 6; ++i) {
          int idx = tid + i * 256; int k = idx >> 3, e = idx & 7;
          px[i] = (k < 128) ? ft1[k] : ft1[128 + e * 64 + (k - 128)];
        }
      }
      float A0[8], A1[8];
      #pragma unroll
      for (int i = 0; i < 8; ++i) { A0[i] = Ax[i]; A1[i] = 0.f; }
      {                                            // FUSED: layer0-h + layer1-x over h0sf
        const float4* h4 = (const float4*)h0sf;
        #pragma unroll
        for (int k2 = 0; k2 < 32; ++k2) {
          const int k = kq * 32 + k2;
          float w0 = wl0[(192 + k) * 32 + r5];
          float w1 = wl1[k * 32 + r5];
          float4 a = h4[k * 2], b = h4[k * 2 + 1];
          FMA_8(A0, w0, a, b);
          FMA_8(A1, w1, a, b);
        }
      }
      {                                            // layer1-h over h1sf
        const float4* h4 = (const float4*)h1sf;
        #pragma unroll
        for (int k2 = 0; k2 < 32; ++k2) {
          const int k = kq * 32 + k2;
          float w = wl1[(256 + k) * 32 + r5];
          float4 a = h4[k * 2], b = h4[k * 2 + 1];
          FMA_8(A1, w, a, b);
        }
      }
      {
        float4* g4 = (float4*)gl0;
        g4[(kq * 32 + r5) * 2]     = make_float4(A0[0], A0[1], A0[2], A0[3]);
        g4[(kq * 32 + r5) * 2 + 1] = make_float4(A0[4], A0[5], A0[6], A0[7]);
        float4* g5 = (float4*)gl1;
        g5[(kq * 32 + r5) * 2]     = make_float4(A1[0], A1[1], A1[2], A1[3]);
        g5[(kq * 32 + r5) * 2 + 1] = make_float4(A1[4], A1[5], A1[6], A1[7]);
      }
      lbar();                                      // S1
      const unsigned g = ((unsigned)(t >> 3) % 7u) + 1u;
      float* ringS = ringM + (size_t)(t & 7) * 4096;
      if (tid < 64) {
        // ---- layer0 reduce + cell -> h0(t) ----
        float s0 = 0.f, s1 = 0.f, s2 = 0.f, s3 = 0.f;
        #pragma unroll
        for (int q = 0; q < 8; ++q) {
          s0 += gl0[q * 256 + tid];       s1 += gl0[q * 256 + 64 + tid];
          s2 += gl0[q * 256 + 128 + tid]; s3 += gl0[q * 256 + 192 + tid];
        }
        float c2 = sigm(s1 + bff) * creg + sigm(s0 + bi) * tanh_(s2 + bgg);
        float h2 = sigm(s3 + bo) * tanh_(c2);
        creg = c2;
        __hip_atomic_store(&ringS[wg * 128 + tid], tagf(h2, g),
                           __ATOMIC_RELAXED, __HIP_MEMORY_SCOPE_AGENT);
        h0sf[wg * 64 + tid] = h2;                  // own slice direct to LDS
      } else if (tid < 128) {
        // ---- layer1 reduce + cell -> h1(t-1) ----
        const int l = tid - 64;
        float h2;
        if (t > 0) {
          float s0 = 0.f, s1 = 0.f, s2 = 0.f, s3 = 0.f;
          #pragma unroll
          for (int q = 0; q < 8; ++q) {
            s0 += gl1[q * 256 + l];       s1 += gl1[q * 256 + 64 + l];
            s2 += gl1[q * 256 + 128 + l]; s3 += gl1[q * 256 + 192 + l];
          }
          float c2 = sigm(s1 + bff) * creg + sigm(s0 + bi) * tanh_(s2 + bgg);
          h2 = sigm(s3 + bo) * tanh_(c2);
          creg = c2;
          __hip_atomic_store(&h1all[(size_t)(t - 1) * 2048 + wg * 64 + l], h2,
                             __ATOMIC_RELAXED, __HIP_MEMORY_SCOPE_AGENT);
          h1sf[wg * 64 + l] = h2;                  // own slice direct to LDS
        } else {
          h2 = h1sf[wg * 64 + l];                  // t=0: republish init h1(-1)
        }
        __hip_atomic_store(&ringS[wg * 128 + 64 + l], tagf(h2, g),
                           __ATOMIC_RELAXED, __HIP_MEMORY_SCOPE_AGENT);
        if (l == 0)                                // un-acked per-step flag
          __hip_atomic_store(&flagsM[wg * 32], t + 1,
                             __ATOMIC_RELAXED, __HIP_MEMORY_SCOPE_AGENT);
        if (t > 0 && ((t - 1) & 7) == 7) {         // acked consumer-facing flag
          asm volatile("s_waitcnt vmcnt(0)" ::: "memory");
          if (l == 0)
            __hip_atomic_store(&flagsBC[((size_t)((t - 1) & 63) * 32 + wg) * 32], t,
                               __ATOMIC_RELAXED, __HIP_MEMORY_SCOPE_AGENT);
        }
      } else if (tid < 160) {
        // ---- poll the 31 remote flags ----
        const int p = tid - 128;
        if (p != wg) {
          const int* fp = flagsM + p * 32;
          while (aload32(fp) < t + 1) __builtin_amdgcn_s_sleep(1);
        }
      }
      lbar();                                      // S2: flags seen, own slices staged
      ull v[8];
      const ull* rp = (const ull*)ringS + tid * 8;
      if (!own) {
        #pragma unroll
        for (int i = 0; i < 8; ++i) v[i] = aload64(rp + i);  // in flight
      }
      if (t + 1 < T_) {
        #pragma unroll
        for (int i = 0; i < 6; ++i) xbuf[tid + i * 256] = px[i];
      }
      lbar();                                      // S3: xbuf(t+1) ready
      #pragma unroll
      for (int i = 0; i < 8; ++i) Ax[i] = 0.f;
      {                                            // next x-part overlaps ring loads
        const float4* x4 = (const float4*)xbuf;
        #pragma unroll
        for (int k = kq * 24; k < kq * 24 + 24; ++k) {
          float w = wl0[k * 32 + r5];
          float4 a = x4[k * 2], b = x4[k * 2 + 1];
          FMA_8(Ax, w, a, b);
        }
      }
      if (!own) {
        while (true) {                             // tag verify; rare retry
          bool ok = true;
          #pragma unroll
          for (int i = 0; i < 8; ++i) {
            unsigned lo = (unsigned)v[i], hi = (unsigned)(v[i] >> 32);
            ok &= ((lo & 7u) == g) & ((hi & 7u) == g);
          }
          if (ok) break;
          __builtin_amdgcn_s_sleep(1);
          #pragma unroll
          for (int i = 0; i < 8; ++i) v[i] = aload64(rp + i);
        }
        const int p8 = tid >> 3, q8 = tid & 7;
        float* dst = (q8 < 4) ? (h0sf + p8 * 64 + q8 * 16)
                              : (h1sf + p8 * 64 + (q8 - 4) * 16);
        float4* d4 = (float4*)dst;
        d4[0] = make_float4(u2f((unsigned)v[0]), u2f((unsigned)(v[0] >> 32)),
                            u2f((unsigned)v[1]), u2f((unsigned)(v[1] >> 32)));
        d4[1] = make_float4(u2f((unsigned)v[2]), u2f((unsigned)(v[2] >> 32)),
                            u2f((unsigned)v[3]), u2f((unsigned)(v[3] >> 32)));
        d4[2] = make_float4(u2f((unsigned)v[4]), u2f((unsigned)(v[4] >> 32)),
                            u2f((unsigned)v[5]), u2f((unsigned)(v[5] >> 32)));
        d4[3] = make_float4(u2f((unsigned)v[6]), u2f((unsigned)(v[6] >> 32)),
                            u2f((unsigned)v[7]), u2f((unsigned)(v[7] >> 32)));
      }
      lbar();                                      // S4
    }
    // ---- epilogue: h1(T_-1) from h0(T_-1), h1(T_-2) ----
    {
      float A1[8] = {0,0,0,0,0,0,0,0};
      {
        const float4* h4 = (const float4*)h0sf;
        #pragma unroll
        for (int k2 = 0; k2 < 32; ++k2) {
          const int k = kq * 32 + k2;
          float w = wl1[k * 32 + r5];
          float4 a = h4[k * 2], b = h4[k * 2 + 1];
          FMA_8(A1, w, a, b);
        }
      }
      {
        const float4* h4 = (const float4*)h1sf;
        #pragma unroll
        for (int k2 = 0; k2 < 32; ++k2) {
          const int k = kq * 32 + k2;
          float w = wl1[(256 + k) * 32 + r5];
          float4 a = h4[k * 2], b = h4[k * 2 + 1];
          FMA_8(A1, w, a, b);
        }
      }
      {
        float4* g5 = (float4*)gl1;
        g5[(kq * 32 + r5) * 2]     = make_float4(A1[0], A1[1], A1[2], A1[3]);
        g5[(kq * 32 + r5) * 2 + 1] = make_float4(A1[4], A1[5], A1[6], A1[7]);
      }
      lbar();
      if (tid >= 64 && tid < 128) {
        const int l = tid - 64;
        float s0 = 0.f, s1 = 0.f, s2 = 0.f, s3 = 0.f;
        #pragma unroll
        for (int q = 0; q < 8; ++q) {
          s0 += gl1[q * 256 + l];       s1 += gl1[q * 256 + 64 + l];
          s2 += gl1[q * 256 + 128 + l]; s3 += gl1[q * 256 + 192 + l];
        }
        float c2 = sigm(s1 + bff) * creg + sigm(s0 + bi) * tanh_(s2 + bgg);
        float h2 = sigm(s3 + bo) * tanh_(c2);
        __hip_atomic_store(&h1all[(size_t)(T_ - 1) * 2048 + wg * 64 + l], h2,
                           __ATOMIC_RELAXED, __HIP_MEMORY_SCOPE_AGENT);
        asm volatile("s_waitcnt vmcnt(0)" ::: "memory");
        if (l == 0)
          __hip_atomic_store(&flagsBC[((size_t)((T_ - 1) & 63) * 32 + wg) * 32], T_,
                             __ATOMIC_RELAXED, __HIP_MEMORY_SCOPE_AGENT);
      }
    }
  } else if (wg < 40) {
    // ============================ phaseC (per e) ============================
    const int e = wg - 32;
    float* wlds = lds;            // [k][256] rows 256-511: 32768 floats
    float* ohl  = lds + 32768;    // 128
    float* gl   = lds + 32896;    // 512
    for (int idx = tid; idx < 32768; idx += 256) {
      int k = idx >> 8, rr = idx & 255;
      wlds[idx] = Whh_o[(256 + rr) * 128 + k];
    }
    float w[128];
    #pragma unroll
    for (int k = 0; k < 128; ++k) w[k] = Whh_o[tid * 128 + k];
    if (tid < 128) ohl[tid] = out_h0[e * 128 + tid];
    float creg = (tid < 128) ? out_c0[e * 128 + tid] : 0.f;
    __syncthreads();
    if (tid == 0) { while (aload32(&flagC[0]) == 0) __builtin_amdgcn_s_sleep(4); }
    __syncthreads();
    const int r0 = tid, r1 = tid + 256;
    float pa = aloadf(&opre1[r0]), pb = aloadf(&opre1[r1]);
    float qa = __bfloat162float(opre2[(size_t)e * 512 + r0]);
    float qb = __bfloat162float(opre2[(size_t)e * 512 + r1]);
    float na = aloadf(&opre1[512 + r0]), nb = aloadf(&opre1[512 + r1]);
    float ma = __bfloat162float(opre2[(size_t)(8 + e) * 512 + r0]);
    float mb = __bfloat162float(opre2[(size_t)(8 + e) * 512 + r1]);
    for (int t = 0; t < T_; ++t) {
      float a0 = pa + qa, a1 = pb + qb;
      pa = na; pb = nb; qa = ma; qb = mb;
      if ((t & 7) == 6 && t + 2 < T_) {            // next chunk ready?
        if (tid == 0) { while (aload32(&flagC[((t + 2) >> 3) * 32]) == 0) __builtin_amdgcn_s_sleep(4); }
        __syncthreads();
      }
      if (t + 2 < T_) {
        na = aloadf(&opre1[(size_t)(t + 2) * 512 + r0]);
        nb = aloadf(&opre1[(size_t)(t + 2) * 512 + r1]);
        ma = __bfloat162float(opre2[((size_t)(t + 2) * 8 + e) * 512 + r0]);
        mb = __bfloat162float(opre2[((size_t)(t + 2) * 8 + e) * 512 + r1]);
      }
      const float4* o4 = (const float4*)ohl;
      #pragma unroll
      for (int kk = 0; kk < 32; ++kk) {
        float4 x = o4[kk];
        a0 = fmaf(w[kk * 4 + 0], x.x, a0); a0 = fmaf(w[kk * 4 + 1], x.y, a0);
        a0 = fmaf(w[kk * 4 + 2], x.z, a0); a0 = fmaf(w[kk * 4 + 3], x.w, a0);
        a1 = fmaf(wlds[(kk * 4 + 0) * 256 + tid], x.x, a1);
        a1 = fmaf(wlds[(kk * 4 + 1) * 256 + tid], x.y, a1);
        a1 = fmaf(wlds[(kk * 4 + 2) * 256 + tid], x.z, a1);
        a1 = fmaf(wlds[(kk * 4 + 3) * 256 + tid], x.w, a1);
      }
      gl[r0] = a0; gl[r1] = a1;
      __syncthreads();
      if (tid < 128) {
        float gi = gl[tid], gf = gl[128 + tid], gg = gl[256 + tid], go = gl[384 + tid];
        float c2 = sigm(gf) * creg + sigm(gi) * tanh_(gg);
        float h2 = sigm(go) * tanh_(c2);
        creg = c2;
        ohl[tid] = h2;
        oh_g[(size_t)t * 1024 + e * 128 + tid] = h2;
      }
      __syncthreads();
    }
  } else {
    // ==================== consumers: fused fc + comm ====================
    const int cb = wg - 40;
    float* h1c    = lds;          // 16384
    float* polAll = lds + 16384;  // 8192
    float* ch0 = lds + 24576; float* cc0 = lds + 25600;
    float* ch1 = lds + 26624; float* cc1 = lds + 27648;
    float* h0b = lds + 28672;     // 1024
    float* glb = lds + 29696;     // 4096
    for (int chunk = cb; chunk < 512; chunk += NCON) {
      const int t0 = chunk * 8;
      if (tid < 32) {
        const int* fp = flagsBC + ((size_t)((t0 + 7) & 63) * 32 + tid) * 32;
        while (aload32(fp) < t0 + 8) __builtin_amdgcn_s_sleep(64);
      }
      __syncthreads();
      {
        const ull* src = (const ull*)(h1all + (size_t)t0 * 2048);
        ull* dst = (ull*)h1c;
        for (int i = tid; i < 8192; i += 256) dst[i] = aload64(src + i);
      }
      __syncthreads();
      {  // fc for 8 ts -> polAll[e][c*8+tt]
        const int c = tid >> 1, half = tid & 1;
        const float bv = bfc[c];
        const float* wrow = Wfc + c * 256;
        for (int tt = 0; tt < 8; ++tt) {
          float a0 = bv, a1 = bv, a2 = bv, a3 = bv;
          const float4* h4 = (const float4*)(h1c + tt * 2048);
          #pragma unroll 4
          for (int k = 0; k < 256; ++k) {
            float wv = wrow[k];
            float4 x = h4[k * 2 + half];
            a0 = fmaf(wv, x.x, a0); a1 = fmaf(wv, x.y, a1);
            a2 = fmaf(wv, x.z, a2); a3 = fmaf(wv, x.w, a3);
          }
          float vv[4] = {a0, a1, a2, a3};
          #pragma unroll
          for (int i = 0; i < 4; ++i) {
            float v = vv[i];
            v = (v > 0.f) ? v : 0.05f * v;
            polAll[(half * 4 + i) * 1024 + c * 8 + tt] = v;
          }
        }
      }
      for (int idx = tid; idx < 1024; idx += 256) { ch0[idx]=0.f; cc0[idx]=0.f; ch1[idx]=0.f; cc1[idx]=0.f; }
      __syncthreads();
      float alpha = 1.0f;
      for (int rd = 0; rd < 3; ++rd) {
        for (int e = 0; e < E_; ++e) {
          comm_cell(wt_c0, b_c0, polAll + e * 1024, ch0, cc0, glb, h0b, alpha, tid);
          comm_cell(wt_c1, b_c1, h0b, ch1, cc1, glb, nullptr, alpha, tid);
        }
        alpha *= 0.333f;
      }
      {  // opre1 epilogue (atomic stores for intra-kernel visibility)
        const int r = tid;
        float A0[8], A1[8];
        #pragma unroll
        for (int tt = 0; tt < 8; ++tt) { A0[tt] = b_o[r]; A1[tt] = b_o[256 + r]; }
        const float4* c04 = (const float4*)cc0;
        const float4* c14 = (const float4*)cc1;
        #pragma unroll 2
        for (int k = 0; k < 128; ++k) {
          float w0 = wt_o1[k * 512 + r], w1 = wt_o1[k * 512 + 256 + r];
          float4 a = c04[k * 2], b = c04[k * 2 + 1];
          FMA_8(A0, w0, a, b);
          FMA_8(A1, w1, a, b);
        }
        #pragma unroll 2
        for (int k = 0; k < 128; ++k) {
          float w0 = wt_o1[(128 + k) * 512 + r], w1 = wt_o1[(128 + k) * 512 + 256 + r];
          float4 a = c14[k * 2], b = c14[k * 2 + 1];
          FMA_8(A0, w0, a, b);
          FMA_8(A1, w1, a, b);
        }
        #pragma unroll
        for (int tt = 0; tt < 8; ++tt) {
          __hip_atomic_store(&opre1[((size_t)(t0 + tt)) * 512 + r], A0[tt],
                             __ATOMIC_RELAXED, __HIP_MEMORY_SCOPE_AGENT);
          __hip_atomic_store(&opre1[((size_t)(t0 + tt)) * 512 + 256 + r], A1[tt],
                             __ATOMIC_RELAXED, __HIP_MEMORY_SCOPE_AGENT);
        }
      }
      __syncthreads();                             // drain opre1 (vmcnt0)
      if (tid == 0)
        __hip_atomic_store(&flagC[chunk * 32], 1, __ATOMIC_RELAXED, __HIP_MEMORY_SCOPE_AGENT);
      __syncthreads();
    }
  }
}

// ---------------------------------------------------------------------------
// phaseD: parallel over t: softmaxes
// ---------------------------------------------------------------------------
__global__ void phaseD(const float* __restrict__ oh_g,
                       const float* __restrict__ Wtar, const float* __restrict__ btar,
                       const float* __restrict__ Wdir, const float* __restrict__ bdir,
                       float* __restrict__ outp) {
  __shared__ float ohl[1024];
  const int t = blockIdx.x, tid = threadIdx.x;  // 64 threads
  for (int idx = tid; idx < 1024; idx += 64) ohl[idx] = oh_g[(size_t)t * 1024 + idx];
  __syncthreads();
  const int f = tid;
  for (int e = 0; e < E_; ++e) {
    float acc = btar[f];
    const float* wr = Wtar + f * 128;
    #pragma unroll 4
    for (int k = 0; k < 128; ++k) acc = fmaf(wr[k], ohl[e * 128 + k], acc);
    float m = acc;
    #pragma unroll
    for (int off = 32; off; off >>= 1) m = fmaxf(m, __shfl_xor(m, off, 64));
    float ex = __expf(acc - m);
    float s = ex;
    #pragma unroll
    for (int off = 32; off; off >>= 1) s += __shfl_xor(s, off, 64);
    outp[((size_t)t * 8 + e) * 64 + f] = ex / s;
  }
  if (tid < 8) {
    int e = tid;
    float d0 = bdir[0], d1 = bdir[1], d2 = bdir[2];
    #pragma unroll 4
    for (int k = 0; k < 128; ++k) {
      float x = ohl[e * 128 + k];
      d0 = fmaf(Wdir[k], x, d0);
      d1 = fmaf(Wdir[128 + k], x, d1);
      d2 = fmaf(Wdir[256 + k], x, d2);
    }
    float m = fmaxf(d0, fmaxf(d1, d2));
    float x0 = __expf(d0 - m), x1 = __expf(d1 - m), x2 = __expf(d2 - m);
    float s = x0 + x1 + x2;
    float* dp = outp + (size_t)T_ * 8 * 64 + ((size_t)t * 8 + e) * 3;
    dp[0] = x0 / s; dp[1] = x1 / s; dp[2] = x2 / s;
  }
}

extern "C" void kernel_launch(void* const* d_in, const int* in_sizes, int n_in,
                              void* d_out, int out_size, void* d_ws, size_t ws_size,
                              hipStream_t stream) {
  (void)in_sizes; (void)n_in; (void)out_size; (void)ws_size;
  const float* feat   = (const float*)d_in[0];
  const float* pre_h0 = (const float*)d_in[1];
  const float* pre_c0 = (const float*)d_in[2];
  const float* out_h0 = (const float*)d_in[3];
  const float* out_c0 = (const float*)d_in[4];
  const float* Wih_p0 = (const float*)d_in[5];
  const float* Whh_p0 = (const float*)d_in[6];
  const float* b_p0   = (const float*)d_in[7];
  const float* Wih_p1 = (const float*)d_in[8];
  const float* Whh_p1 = (const float*)d_in[9];
  const float* b_p1   = (const float*)d_in[10];
  const float* Wfc    = (const float*)d_in[11];
  const float* bfc    = (const float*)d_in[12];
  const float* Wih_c0 = (const float*)d_in[13];
  const float* Whh_c0 = (const float*)d_in[14];
  const float* b_c0   = (const float*)d_in[15];
  const float* Wih_c1 = (const float*)d_in[16];
  const float* Whh_c1 = (const float*)d_in[17];
  const float* b_c1   = (const float*)d_in[18];
  const float* Wih_o  = (const float*)d_in[19];
  const float* Whh_o  = (const float*)d_in[20];
  const float* b_o    = (const float*)d_in[21];
  const float* Wtar   = (const float*)d_in[22];
  const float* btar   = (const float*)d_in[23];
  const float* Wdir   = (const float*)d_in[24];
  const float* bdir   = (const float*)d_in[25];
  float* outp = (float*)d_out;

  float* ws = (float*)d_ws;
  size_t off = 0;
  float* opre1    = ws + off; off += (size_t)T_ * 512;
  float* oh_g     = ws + off; off += (size_t)T_ * E_ * 128;
  float* wt_p0    = ws + off; off += (size_t)448 * 1024;
  float* wt_p1    = ws + off; off += (size_t)512 * 1024;
  float* wt_c0    = ws + off; off += (size_t)256 * 512;
  float* wt_c1    = ws + off; off += (size_t)256 * 512;
  float* wt_o1    = ws + off; off += (size_t)256 * 512;
  float* wt_o2    = ws + off; off += (size_t)192 * 512;
  __hip_bfloat16* opre2 = (__hip_bfloat16*)(ws + off);
  off += (size_t)T_ * E_ * 512 / 2;
  float* h1all  = ws + off; off += (size_t)T_ * 2048;
  float* ringM  = ws + off; off += (size_t)8 * 4096;    // tagged floats, depth 8
  int* flags    = (int*)(ws + off);
  int* flagsM   = flags;                                 // 32 * 32
  int* flagsBC  = flags + (size_t)32 * 32;               // 64*32*32
  int* flagC    = flags + (size_t)32 * 32 + (size_t)64 * 32 * 32;  // 512*32
  int* zbase    = (int*)ringM;   // zero span: ring + all flags

  initK<<<dim3(1024), dim3(256), 0, stream>>>(
      Wih_p0, Whh_p0, Wih_p1, Whh_p1, Wih_c0, Whh_c0, Wih_c1, Whh_c1, Wih_o,
      wt_p0, wt_p1, wt_c0, wt_c1, wt_o1, wt_o2, zbase);
  opre2K<<<dim3(T_), dim3(256), 0, stream>>>(feat, wt_o2, opre2);
  megaK<<<dim3(32 + 8 + NCON), dim3(256), 0, stream>>>(
      feat, pre_h0, pre_c0, wt_p0, wt_p1, b_p0, b_p1,
      ringM, flagsM, h1all, flagsBC,
      Wfc, bfc, wt_c0, wt_c1, b_c0, b_c1, wt_o1, b_o, opre1, flagC,
      opre2, Whh_o, out_h0, out_c0, oh_g);
  phaseD<<<dim3(T_), dim3(64), 0, stream>>>(oh_g, Wtar, btar, Wdir, bdir, outp);
}

// Round 5
// 18008.482 us; speedup vs baseline: 1.4023x; 1.4023x over previous
//
#include <hip/hip_runtime.h>
#include <hip/hip_bf16.h>

// Sizes from the reference
#define T_   4096
#define E_   8
#define NCON 176   // consumer blocks (total grid = 32 + 32 + 8 + NCON = 248)

typedef unsigned long long ull;

__device__ __forceinline__ float sigm(float x)  { return 1.0f / (1.0f + __expf(-x)); }
__device__ __forceinline__ float tanh_(float x) { return 1.0f - 2.0f / (__expf(2.0f * x) + 1.0f); }

__device__ __forceinline__ ull aload64(const ull* p) {
  return __hip_atomic_load(p, __ATOMIC_RELAXED, __HIP_MEMORY_SCOPE_AGENT);
}
__device__ __forceinline__ int aload32(const int* p) {
  return __hip_atomic_load(p, __ATOMIC_RELAXED, __HIP_MEMORY_SCOPE_AGENT);
}
__device__ __forceinline__ float aloadf(const float* p) {
  return __hip_atomic_load(p, __ATOMIC_RELAXED, __HIP_MEMORY_SCOPE_AGENT);
}
// barrier draining LDS (lgkm) but not vector memory
__device__ __forceinline__ void lbar() {
  asm volatile("s_waitcnt lgkmcnt(0)\n\ts_barrier" ::: "memory");
}

#define FMA_8(ACC, W, VA, VB)                                   \
  ACC[0] = fmaf((W), (VA).x, ACC[0]); ACC[1] = fmaf((W), (VA).y, ACC[1]); \
  ACC[2] = fmaf((W), (VA).z, ACC[2]); ACC[3] = fmaf((W), (VA).w, ACC[3]); \
  ACC[4] = fmaf((W), (VB).x, ACC[4]); ACC[5] = fmaf((W), (VB).y, ACC[5]); \
  ACC[6] = fmaf((W), (VB).z, ACC[6]); ACC[7] = fmaf((W), (VB).w, ACC[7]);

// ---------------------------------------------------------------------------
// initK: K-major packed weight copies + zero rings / flags.
// ---------------------------------------------------------------------------
__global__ void initK(const float* __restrict__ Wih_p0, const float* __restrict__ Whh_p0,
                      const float* __restrict__ Wih_p1, const float* __restrict__ Whh_p1,
                      const float* __restrict__ Wih_c0, const float* __restrict__ Whh_c0,
                      const float* __restrict__ Wih_c1, const float* __restrict__ Whh_c1,
                      const float* __restrict__ Wih_o,
                      float* wt_p0, float* wt_p1, float* wt_c0, float* wt_c1,
                      float* wt_o1, float* wt_o2, int* zbase) {
  const int NW = 458752 + 524288 + 131072 + 131072 + 131072 + 98304;
  // zero: h0ring 65536 + h1ring 16384 + flagsA 65536 + flagB1 65536
  //       + flagsBC 65536 + flagC 16384
  const int NZ = 65536 + 16384 + 65536 + 65536 + 65536 + 16384;
  const int NTOT = NW + NZ;
  const int gsz = gridDim.x * blockDim.x;
  for (int i = blockIdx.x * blockDim.x + threadIdx.x; i < NTOT; i += gsz) {
    int idx = i;
    if (idx < 458752) { int k = idx >> 10, c = idx & 1023;
      int wg = c >> 5, r5 = c & 31, gate = r5 >> 3, jl = r5 & 7;
      int col = gate * 256 + wg * 8 + jl;
      wt_p0[idx] = (k < 192) ? Wih_p0[col * 192 + k] : Whh_p0[col * 256 + (k - 192)]; continue; }
    idx -= 458752;
    if (idx < 524288) { int k = idx >> 10, c = idx & 1023;
      int wg = c >> 5, r5 = c & 31, gate = r5 >> 3, jl = r5 & 7;
      int col = gate * 256 + wg * 8 + jl;
      wt_p1[idx] = (k < 256) ? Wih_p1[col * 256 + k] : Whh_p1[col * 256 + (k - 256)]; continue; }
    idx -= 524288;
    if (idx < 131072) { int k = idx >> 9, r = idx & 511;
      wt_c0[idx] = (k < 128) ? Wih_c0[r * 128 + k] : Whh_c0[r * 128 + (k - 128)]; continue; }
    idx -= 131072;
    if (idx < 131072) { int k = idx >> 9, r = idx & 511;
      wt_c1[idx] = (k < 128) ? Wih_c1[r * 128 + k] : Whh_c1[r * 128 + (k - 128)]; continue; }
    idx -= 131072;
    if (idx < 131072) { int k = idx >> 9, r = idx & 511;
      wt_o1[idx] = Wih_o[r * 448 + k]; continue; }
    idx -= 131072;
    if (idx < 98304) { int k = idx >> 9, r = idx & 511;
      wt_o2[idx] = Wih_o[r * 448 + 256 + k]; continue; }
    idx -= 98304;
    zbase[idx] = 0;
  }
}

// ---------------------------------------------------------------------------
// opre2K: parallel over t. opre2[t][e][512] = Wih_o[:,256:448] @ x(t,e)  (bf16)
// ---------------------------------------------------------------------------
__global__ void opre2K(const float* __restrict__ feat, const float* __restrict__ wt_o2,
                       __hip_bfloat16* __restrict__ opre2) {
  __shared__ float xb[192 * 8];
  const int t = blockIdx.x, tid = threadIdx.x;
  const float* ft = feat + (size_t)t * 640;
  for (int idx = tid; idx < 192 * 8; idx += 256) {
    int k = idx >> 3, e = idx & 7;
    xb[idx] = (k < 128) ? ft[k] : ft[128 + e * 64 + (k - 128)];
  }
  __syncthreads();
  const int r = tid;
  float A0[8] = {0,0,0,0,0,0,0,0};
  float A1[8] = {0,0,0,0,0,0,0,0};
  const float4* x4 = (const float4*)xb;
  #pragma unroll 2
  for (int k = 0; k < 192; ++k) {
    float w0 = wt_o2[k * 512 + r];
    float w1 = wt_o2[k * 512 + 256 + r];
    float4 a = x4[k * 2], b = x4[k * 2 + 1];
    FMA_8(A0, w0, a, b);
    FMA_8(A1, w1, a, b);
  }
  #pragma unroll
  for (int e = 0; e < 8; ++e) {
    opre2[((size_t)t * 8 + e) * 512 + r]       = __float2bfloat16(A0[e]);
    opre2[((size_t)t * 8 + e) * 512 + 256 + r] = __float2bfloat16(A1[e]);
  }
}

// ---------------------------------------------------------------------------
// comm cell (unchanged math)
// ---------------------------------------------------------------------------
__device__ __forceinline__ void comm_cell(
    const float* __restrict__ wt, const float* __restrict__ bias,
    const float* xin, float* hL, float* cL, float* glb, float* hout,
    float alpha, int tid) {
  const int r = tid;
  float A0[8] = {0,0,0,0,0,0,0,0};
  float A1[8] = {0,0,0,0,0,0,0,0};
  const float4* x4 = (const float4*)xin;
  #pragma unroll 2
  for (int k = 0; k < 128; ++k) {
    float w0 = wt[k * 512 + r];
    float w1 = wt[k * 512 + 256 + r];
    float4 a = x4[k * 2], b = x4[k * 2 + 1];
    FMA_8(A0, w0, a, b);
    FMA_8(A1, w1, a, b);
  }
  const float4* h4 = (const float4*)hL;
  #pragma unroll 2
  for (int k = 0; k < 128; ++k) {
    float w0 = wt[(128 + k) * 512 + r];
    float w1 = wt[(128 + k) * 512 + 256 + r];
    float4 a = h4[k * 2], b = h4[k * 2 + 1];
    FMA_8(A0, w0, a, b);
    FMA_8(A1, w1, a, b);
  }
  {
    float4* g4 = (float4*)glb;
    g4[r * 2]             = make_float4(A0[0], A0[1], A0[2], A0[3]);
    g4[r * 2 + 1]         = make_float4(A0[4], A0[5], A0[6], A0[7]);
    g4[(256 + r) * 2]     = make_float4(A1[0], A1[1], A1[2], A1[3]);
    g4[(256 + r) * 2 + 1] = make_float4(A1[4], A1[5], A1[6], A1[7]);
  }
  __syncthreads();
  for (int idx = tid; idx < 1024; idx += 256) {
    int jj = idx >> 3, tt = idx & 7;
    float gi = glb[jj * 8 + tt]         + bias[jj];
    float gf = glb[(128 + jj) * 8 + tt] + bias[128 + jj];
    float gg = glb[(256 + jj) * 8 + tt] + bias[256 + jj];
    float go = glb[(384 + jj) * 8 + tt] + bias[384 + jj];
    float cold = cL[idx], hold = hL[idx];
    float c2 = sigm(gf) * cold + sigm(gi) * tanh_(gg);
    float h2 = sigm(go) * tanh_(c2);
    float hb = fmaf(alpha, h2 - hold, hold);
    float cb = fmaf(alpha, c2 - cold, cold);
    hL[idx] = hb; cL[idx] = cb;
    if (hout) hout[idx] = hb;
  }
  __syncthreads();
}

// ---------------------------------------------------------------------------
// MEGA kernel: 248 blocks, 256 thr, 155648 B LDS => 1 block/CU => all 248
// resident simultaneously. R1 protocol (acked per-step flag, load-once, no
// tags) with two critical-path diets:
//  (1) G2 wave0 acks ONLY the h1ring store before the flag; h1all store +
//      8-step flagsBC ack are done by wave3 (tid 192..255), off the path.
//  (2) Consumers + G1 back-pressure poll a separate 8-step flagsBC array
//      (sleep 64/16); per-step flags are touched only by the detect lanes.
//   blocks 0-31  : G1 layer0; h0ring depth 32, free-runs (lag-24 backpressure)
//   blocks 32-63 : G2 layer1; h1ring depth 8; prefetch-polls h0(t+2)
//   blocks 64-71 : phaseC per-e output LSTM
//   blocks 72-   : consumers: fused fc+comm per 8-t chunk (flagsBC-gated)
// ---------------------------------------------------------------------------
__launch_bounds__(256, 1)
__global__ void megaK(const float* __restrict__ feat,
                      const float* __restrict__ pre_h0, const float* __restrict__ pre_c0,
                      const float* __restrict__ wt_p0, const float* __restrict__ wt_p1,
                      const float* __restrict__ b_p0, const float* __restrict__ b_p1,
                      float* __restrict__ h0ring, float* __restrict__ h1ring,
                      float* __restrict__ h1all,
                      int* __restrict__ flagsA, int* __restrict__ flagB1,
                      int* __restrict__ flagsBC,
                      const float* __restrict__ Wfc, const float* __restrict__ bfc,
                      const float* __restrict__ wt_c0, const float* __restrict__ wt_c1,
                      const float* __restrict__ b_c0, const float* __restrict__ b_c1,
                      const float* __restrict__ wt_o1, const float* __restrict__ b_o,
                      float* __restrict__ opre1, int* __restrict__ flagC,
                      const __hip_bfloat16* __restrict__ opre2,
                      const float* __restrict__ Whh_o, const float* __restrict__ out_h0,
                      const float* __restrict__ out_c0, float* __restrict__ oh_g) {
  __shared__ float lds[38912];   // 155,648 B
  const int wg = blockIdx.x, tid = threadIdx.x;

  if (wg < 32) {
    // ============================ G1: layer0 (32 blocks) ============================
    float* wl   = lds;            // 14336: weights [k][32], k<448
    float* xbuf = lds + 14336;    // 1536
    float* hsf  = lds + 15872;    // 2048
    float* gl   = lds + 17920;    // 2048 partials
    const int r5 = tid & 31, kq = tid >> 5;
    for (int idx = tid; idx < 14336; idx += 256)
      wl[idx] = wt_p0[(size_t)(idx >> 5) * 1024 + wg * 32 + (idx & 31)];
    float creg = 0.f, bi = 0.f, bff = 0.f, bg = 0.f, bo = 0.f;
    if (tid < 64) {
      const int jl = tid >> 3, e = tid & 7, j = wg * 8 + jl;
      creg = pre_c0[(e * 2 + 0) * 256 + j];
      bi = b_p0[j]; bff = b_p0[256 + j]; bg = b_p0[512 + j]; bo = b_p0[768 + j];
    }
    for (int idx = tid; idx < 2048; idx += 256) {
      int k = idx >> 3, e = idx & 7;
      hsf[idx] = pre_h0[(e * 2 + 0) * 256 + k];
    }
    for (int idx = tid; idx < 1536; idx += 256) {
      int k = idx >> 3, e = idx & 7;
      xbuf[idx] = (k < 128) ? feat[k] : feat[128 + e * 64 + (k - 128)];
    }
    __syncthreads();
    float Ax[8] = {0,0,0,0,0,0,0,0};
    {
      const float4* x4 = (const float4*)xbuf;
      #pragma unroll
      for (int k = kq * 24; k < kq * 24 + 24; ++k) {
        float w = wl[k * 32 + r5];
        float4 a = x4[k * 2], b = x4[k * 2 + 1];
        FMA_8(Ax, w, a, b);
      }
    }
    for (int t = 0; t < T_; ++t) {
      float px[6];
      if (t + 1 < T_) {
        const float* ft1 = feat + (size_t)(t + 1) * 640;
        #pragma unroll
        for (int i = 0; i < 6; ++i) {
          int idx = tid + i * 256; int k = idx >> 3, e = idx & 7;
          px[i] = (k < 128) ? ft1[k] : ft1[128 + e * 64 + (k - 128)];
        }
      }
      float A[8];
      #pragma unroll
      for (int i = 0; i < 8; ++i) A[i] = Ax[i];
      {
        const float4* h4 = (const float4*)hsf;
        #pragma unroll
        for (int k2 = 0; k2 < 32; ++k2) {
          const int k = kq * 32 + k2;
          float w = wl[(192 + k) * 32 + r5];
          float4 a = h4[k * 2], b = h4[k * 2 + 1];
          FMA_8(A, w, a, b);
        }
      }
      {
        float4* g4 = (float4*)gl;
        g4[(kq * 32 + r5) * 2]     = make_float4(A[0], A[1], A[2], A[3]);
        g4[(kq * 32 + r5) * 2 + 1] = make_float4(A[4], A[5], A[6], A[7]);
      }
      if (t >= 24 && tid >= 224) {                 // back-pressure, lag 24 (8-step gran)
        const int t2 = (t - 24) | 7;
        const int* fp = flagsBC + ((size_t)(t2 & 63) * 32 + (tid - 224)) * 32;
        while (aload32(fp) < t2 + 1) __builtin_amdgcn_s_sleep(16);
      }
      lbar();                                      // S1
      if (tid < 64) {
        float s0 = 0.f, s1 = 0.f, s2 = 0.f, s3 = 0.f;
        #pragma unroll
        for (int q = 0; q < 8; ++q) {
          s0 += gl[q * 256 + tid];       s1 += gl[q * 256 + 64 + tid];
          s2 += gl[q * 256 + 128 + tid]; s3 += gl[q * 256 + 192 + tid];
        }
        float c2 = sigm(s1 + bff) * creg + sigm(s0 + bi) * tanh_(s2 + bg);
        float h2 = sigm(s3 + bo) * tanh_(c2);
        creg = c2;
        __hip_atomic_store(&h0ring[(size_t)(t & 31) * 2048 + wg * 64 + tid], h2,
                           __ATOMIC_RELAXED, __HIP_MEMORY_SCOPE_AGENT);
        asm volatile("s_waitcnt vmcnt(0)" ::: "memory");   // ring-store ack only
        if (tid == 0)
          __hip_atomic_store(&flagsA[((size_t)(t & 63) * 32 + wg) * 32], t + 1,
                             __ATOMIC_RELAXED, __HIP_MEMORY_SCOPE_AGENT);
      }
      if (t + 1 >= T_) break;
      #pragma unroll
      for (int i = 0; i < 6; ++i) xbuf[tid + i * 256] = px[i];
      if (tid >= 64 && tid < 96) {                 // wave1 detects h0(t) flags
        const int* fp = flagsA + ((size_t)(t & 63) * 32 + (tid - 64)) * 32;
        while (aload32(fp) < t + 1) __builtin_amdgcn_s_sleep(1);
      }
      lbar();                                      // S3: xbuf staged + flags seen
      ull v[4];
      {
        const ull* s8 = (const ull*)(h0ring + (size_t)(t & 31) * 2048);
        #pragma unroll
        for (int i = 0; i < 4; ++i) v[i] = aload64(s8 + tid * 4 + i);
      }
      #pragma unroll
      for (int i = 0; i < 8; ++i) Ax[i] = 0.f;
      {                                            // x-matvec overlaps the ring loads
        const float4* x4 = (const float4*)xbuf;
        #pragma unroll
        for (int k = kq * 24; k < kq * 24 + 24; ++k) {
          float w = wl[k * 32 + r5];
          float4 a = x4[k * 2], b = x4[k * 2 + 1];
          FMA_8(Ax, w, a, b);
        }
      }
      {
        ull* d8 = (ull*)hsf;
        #pragma unroll
        for (int i = 0; i < 4; ++i) d8[tid * 4 + i] = v[i];
      }
      lbar();                                      // S4
    }
  } else if (wg < 64) {
    // ============================ G2: layer1 (32 blocks) ============================
    const int wgl = wg - 32;
    float* wl  = lds;             // 16384: weights [k][32], k<512
    float* xh0 = lds + 16384;     // 2048
    float* hsf = lds + 18432;     // 2048
    float* gl  = lds + 20480;     // 2048
    const int r5 = tid & 31, kq = tid >> 5;
    for (int idx = tid; idx < 16384; idx += 256)
      wl[idx] = wt_p1[(size_t)(idx >> 5) * 1024 + wgl * 32 + (idx & 31)];
    float creg = 0.f, bi = 0.f, bff = 0.f, bg = 0.f, bo = 0.f;
    if (tid < 64) {
      const int jl = tid >> 3, e = tid & 7, j = wgl * 8 + jl;
      creg = pre_c0[(e * 2 + 1) * 256 + j];
      bi = b_p1[j]; bff = b_p1[256 + j]; bg = b_p1[512 + j]; bo = b_p1[768 + j];
    }
    for (int idx = tid; idx < 2048; idx += 256) {
      int k = idx >> 3, e = idx & 7;
      hsf[idx] = pre_h0[(e * 2 + 1) * 256 + k];
    }
    __syncthreads();
    // prologue: wait for h0(0) and h0(1)
    if (tid >= 64 && tid < 128) {
      const int lane = tid - 64;
      const int slot = lane >> 5, b = lane & 31;
      const int* fp = flagsA + ((size_t)slot * 32 + b) * 32;
      while (aload32(fp) < slot + 1) __builtin_amdgcn_s_sleep(1);
    }
    __syncthreads();
    ull v0[4];
    {
      const ull* s8 = (const ull*)h0ring;          // slot 0 = h0(0)
      #pragma unroll
      for (int i = 0; i < 4; ++i) v0[i] = aload64(s8 + tid * 4 + i);
    }
    {
      ull* d8 = (ull*)xh0;
      #pragma unroll
      for (int i = 0; i < 4; ++i) d8[tid * 4 + i] = v0[i];
    }
    lbar();
    float Ax[8] = {0,0,0,0,0,0,0,0};
    {
      const float4* x4 = (const float4*)xh0;
      #pragma unroll
      for (int k = kq * 32; k < kq * 32 + 32; ++k) {
        float w = wl[k * 32 + r5];
        float4 a = x4[k * 2], b = x4[k * 2 + 1];
        FMA_8(Ax, w, a, b);
      }
    }
    {
      const ull* s8 = (const ull*)(h0ring + 2048); // slot 1 = h0(1), prefetch
      #pragma unroll
      for (int i = 0; i < 4; ++i) v0[i] = aload64(s8 + tid * 4 + i);
    }
    for (int t = 0; t < T_; ++t) {
      float A[8];
      #pragma unroll
      for (int i = 0; i < 8; ++i) A[i] = Ax[i];
      {
        const float4* h4 = (const float4*)hsf;
        #pragma unroll
        for (int k2 = 0; k2 < 32; ++k2) {
          const int k = kq * 32 + k2;
          float w = wl[(256 + k) * 32 + r5];
          float4 a = h4[k * 2], b = h4[k * 2 + 1];
          FMA_8(A, w, a, b);
        }
      }
      {
        float4* g4 = (float4*)gl;
        g4[(kq * 32 + r5) * 2]     = make_float4(A[0], A[1], A[2], A[3]);
        g4[(kq * 32 + r5) * 2 + 1] = make_float4(A[4], A[5], A[6], A[7]);
      }
      lbar();                                      // S1
      if (tid < 64) {
        float s0 = 0.f, s1 = 0.f, s2 = 0.f, s3 = 0.f;
        #pragma unroll
        for (int q = 0; q < 8; ++q) {
          s0 += gl[q * 256 + tid];       s1 += gl[q * 256 + 64 + tid];
          s2 += gl[q * 256 + 128 + tid]; s3 += gl[q * 256 + 192 + tid];
        }
        float c2 = sigm(s1 + bff) * creg + sigm(s0 + bi) * tanh_(s2 + bg);
        float h2 = sigm(s3 + bo) * tanh_(c2);
        creg = c2;
        __hip_atomic_store(&h1ring[(size_t)(t & 7) * 2048 + wgl * 64 + tid], h2,
                           __ATOMIC_RELAXED, __HIP_MEMORY_SCOPE_AGENT);
        hsf[wgl * 64 + tid] = h2;                  // own slice for wave3's h1all duty
        asm volatile("s_waitcnt vmcnt(0)" ::: "memory");   // ring-store ack ONLY
        if (tid == 0)
          __hip_atomic_store(&flagB1[((size_t)(t & 63) * 32 + wgl) * 32], t + 1,
                             __ATOMIC_RELAXED, __HIP_MEMORY_SCOPE_AGENT);
      }
      if (t + 1 >= T_) break;
      // wave1: detect own-group h1(t) + prefetch-poll h0(t+2)
      if (tid >= 64 && tid < 128) {
        const int lane = tid - 64;
        if (lane < 32) {
          const int* fp = flagB1 + ((size_t)(t & 63) * 32 + lane) * 32;
          while (aload32(fp) < t + 1) __builtin_amdgcn_s_sleep(1);
        } else if (t + 2 < T_) {
          const int* fp = flagsA + ((size_t)((t + 2) & 63) * 32 + (lane - 32)) * 32;
          while (aload32(fp) < t + 3) __builtin_amdgcn_s_sleep(1);
        }
      }
      lbar();                                      // S2
      if (tid >= 192) {                            // wave3: h1all + flagsBC, off path
        const int l = tid - 192;
        float h2o = hsf[wgl * 64 + l];
        __hip_atomic_store(&h1all[(size_t)t * 2048 + wgl * 64 + l], h2o,
                           __ATOMIC_RELAXED, __HIP_MEMORY_SCOPE_AGENT);
        if ((t & 7) == 7) {
          asm volatile("s_waitcnt vmcnt(0)" ::: "memory");
          if (l == 0)
            __hip_atomic_store(&flagsBC[((size_t)(t & 63) * 32 + wgl) * 32], t + 1,
                               __ATOMIC_RELAXED, __HIP_MEMORY_SCOPE_AGENT);
        }
      }
      ull v1[4];
      {                                            // issue h1(t) loads (in flight)
        const ull* s8 = (const ull*)(h1ring + (size_t)(t & 7) * 2048);
        #pragma unroll
        for (int i = 0; i < 4; ++i) v1[i] = aload64(s8 + tid * 4 + i);
      }
      {                                            // stage xh0 = h0(t+1) from regs
        ull* d8 = (ull*)xh0;
        #pragma unroll
        for (int i = 0; i < 4; ++i) d8[tid * 4 + i] = v0[i];
      }
      lbar();                                      // S3: xh0 staged (v1 still in flight)
      if (t + 2 < T_) {                            // prefetch h0(t+2) for next iter
        const ull* s8 = (const ull*)(h0ring + (size_t)((t + 2) & 31) * 2048);
        #pragma unroll
        for (int i = 0; i < 4; ++i) v0[i] = aload64(s8 + tid * 4 + i);
      }
      #pragma unroll
      for (int i = 0; i < 8; ++i) Ax[i] = 0.f;
      {                                            // x-part: overlaps v1 latency
        const float4* x4 = (const float4*)xh0;
        #pragma unroll
        for (int k = kq * 32; k < kq * 32 + 32; ++k) {
          float w = wl[k * 32 + r5];
          float4 a = x4[k * 2], b = x4[k * 2 + 1];
          FMA_8(Ax, w, a, b);
        }
      }
      {
        ull* d8 = (ull*)hsf;
        #pragma unroll
        for (int i = 0; i < 4; ++i) d8[tid * 4 + i] = v1[i];
      }
      lbar();                                      // S4
    }
    // epilogue: h1all(T_-1) + final flagsBC (wave3)
    lbar();
    if (tid >= 192) {
      const int l = tid - 192;
      float h2o = hsf[wgl * 64 + l];               // own slice of h1(T_-1)
      __hip_atomic_store(&h1all[(size_t)(T_ - 1) * 2048 + wgl * 64 + l], h2o,
                         __ATOMIC_RELAXED, __HIP_MEMORY_SCOPE_AGENT);
      asm volatile("s_waitcnt vmcnt(0)" ::: "memory");
      if (l == 0)
        __hip_atomic_store(&flagsBC[((size_t)((T_ - 1) & 63) * 32 + wgl) * 32], T_,
                           __ATOMIC_RELAXED, __HIP_MEMORY_SCOPE_AGENT);
    }
  } else if (wg < 72) {
    // ============================ phaseC (per e) ============================
    const int e = wg - 64;
    float* wlds = lds;            // [k][256] rows 256-511: 32768 floats
    float* ohl  = lds + 32768;    // 128
    float* gl   = lds + 32896;    // 512
    for (int idx = tid; idx < 32768; idx += 256) {
      int k = idx >> 8, rr = idx & 255;
      wlds[idx] = Whh_o[(256 + rr) * 128 + k];
    }
    float w[128];
    #pragma unroll
    for (int k = 0; k < 128; ++k) w[k] = Whh_o[tid * 128 + k];
    if (tid < 128) ohl[tid] = out_h0[e * 128 + tid];
    float creg = (tid < 128) ? out_c0[e * 128 + tid] : 0.f;
    __syncthreads();
    if (tid == 0) { while (aload32(&flagC[0]) == 0) __builtin_amdgcn_s_sleep(4); }
    __syncthreads();
    const int r0 = tid, r1 = tid + 256;
    float pa = aloadf(&opre1[r0]), pb = aloadf(&opre1[r1]);
    float qa = __bfloat162float(opre2[(size_t)e * 512 + r0]);
    float qb = __bfloat162float(opre2[(size_t)e * 512 + r1]);
    float na = aloadf(&opre1[512 + r0]), nb = aloadf(&opre1[512 + r1]);
    float ma = __bfloat162float(opre2[(size_t)(8 + e) * 512 + r0]);
    float mb = __bfloat162float(opre2[(size_t)(8 + e) * 512 + r1]);
    for (int t = 0; t < T_; ++t) {
      float a0 = pa + qa, a1 = pb + qb;
      pa = na; pb = nb; qa = ma; qb = mb;
      if ((t & 7) == 6 && t + 2 < T_) {            // next chunk ready?
        if (tid == 0) { while (aload32(&flagC[((t + 2) >> 3) * 32]) == 0) __builtin_amdgcn_s_sleep(4); }
        __syncthreads();
      }
      if (t + 2 < T_) {
        na = aloadf(&opre1[(size_t)(t + 2) * 512 + r0]);
        nb = aloadf(&opre1[(size_t)(t + 2) * 512 + r1]);
        ma = __bfloat162float(opre2[((size_t)(t + 2) * 8 + e) * 512 + r0]);
        mb = __bfloat162float(opre2[((size_t)(t + 2) * 8 + e) * 512 + r1]);
      }
      const float4* o4 = (const float4*)ohl;
      #pragma unroll
      for (int kk = 0; kk < 32; ++kk) {
        float4 x = o4[kk];
        a0 = fmaf(w[kk * 4 + 0], x.x, a0); a0 = fmaf(w[kk * 4 + 1], x.y, a0);
        a0 = fmaf(w[kk * 4 + 2], x.z, a0); a0 = fmaf(w[kk * 4 + 3], x.w, a0);
        a1 = fmaf(wlds[(kk * 4 + 0) * 256 + tid], x.x, a1);
        a1 = fmaf(wlds[(kk * 4 + 1) * 256 + tid], x.y, a1);
        a1 = fmaf(wlds[(kk * 4 + 2) * 256 + tid], x.z, a1);
        a1 = fmaf(wlds[(kk * 4 + 3) * 256 + tid], x.w, a1);
      }
      gl[r0] = a0; gl[r1] = a1;
      __syncthreads();
      if (tid < 128) {
        float gi = gl[tid], gf = gl[128 + tid], gg = gl[256 + tid], go = gl[384 + tid];
        float c2 = sigm(gf) * creg + sigm(gi) * tanh_(gg);
        float h2 = sigm(go) * tanh_(c2);
        creg = c2;
        ohl[tid] = h2;
        oh_g[(size_t)t * 1024 + e * 128 + tid] = h2;
      }
      __syncthreads();
    }
  } else {
    // ==================== consumers: fused fc + comm ====================
    const int cb = wg - 72;
    float* h1c    = lds;          // 16384
    float* polAll = lds + 16384;  // 8192
    float* ch0 = lds + 24576; float* cc0 = lds + 25600;
    float* ch1 = lds + 26624; float* cc1 = lds + 27648;
    float* h0b = lds + 28672;     // 1024
    float* glb = lds + 29696;     // 4096
    for (int chunk = cb; chunk < 512; chunk += NCON) {
      const int t0 = chunk * 8;
      if (tid < 32) {
        const int* fp = flagsBC + ((size_t)((t0 + 7) & 63) * 32 + tid) * 32;
        while (aload32(fp) < t0 + 8) __builtin_amdgcn_s_sleep(64);
      }
      __syncthreads();
      {
        const ull* src = (const ull*)(h1all + (size_t)t0 * 2048);
        ull* dst = (ull*)h1c;
        for (int i = tid; i < 8192; i += 256) dst[i] = aload64(src + i);
      }
      __syncthreads();
      {  // fc for 8 ts -> polAll[e][c*8+tt]
        const int c = tid >> 1, half = tid & 1;
        const float bv = bfc[c];
        const float* wrow = Wfc + c * 256;
        for (int tt = 0; tt < 8; ++tt) {
          float a0 = bv, a1 = bv, a2 = bv, a3 = bv;
          const float4* h4 = (const float4*)(h1c + tt * 2048);
          #pragma unroll 4
          for (int k = 0; k < 256; ++k) {
            float wv = wrow[k];
            float4 x = h4[k * 2 + half];
            a0 = fmaf(wv, x.x, a0); a1 = fmaf(wv, x.y, a1);
            a2 = fmaf(wv, x.z, a2); a3 = fmaf(wv, x.w, a3);
          }
          float vv[4] = {a0, a1, a2, a3};
          #pragma unroll
          for (int i = 0; i < 4; ++i) {
            float v = vv[i];
            v = (v > 0.f) ? v : 0.05f * v;
            polAll[(half * 4 + i) * 1024 + c * 8 + tt] = v;
          }
        }
      }
      for (int idx = tid; idx < 1024; idx += 256) { ch0[idx]=0.f; cc0[idx]=0.f; ch1[idx]=0.f; cc1[idx]=0.f; }
      __syncthreads();
      float alpha = 1.0f;
      for (int rd = 0; rd < 3; ++rd) {
        for (int e = 0; e < E_; ++e) {
          comm_cell(wt_c0, b_c0, polAll + e * 1024, ch0, cc0, glb, h0b, alpha, tid);
          comm_cell(wt_c1, b_c1, h0b, ch1, cc1, glb, nullptr, alpha, tid);
        }
        alpha *= 0.333f;
      }
      {  // opre1 epilogue (atomic stores for intra-kernel visibility)
        const int r = tid;
        float A0[8], A1[8];
        #pragma unroll
        for (int tt = 0; tt < 8; ++tt) { A0[tt] = b_o[r]; A1[tt] = b_o[256 + r]; }
        const float4* c04 = (const float4*)cc0;
        const float4* c14 = (const float4*)cc1;
        #pragma unroll 2
        for (int k = 0; k < 128; ++k) {
          float w0 = wt_o1[k * 512 + r], w1 = wt_o1[k * 512 + 256 + r];
          float4 a = c04[k * 2], b = c04[k * 2 + 1];
          FMA_8(A0, w0, a, b);
          FMA_8(A1, w1, a, b);
        }
        #pragma unroll 2
        for (int k = 0; k < 128; ++k) {
          float w0 = wt_o1[(128 + k) * 512 + r], w1 = wt_o1[(128 + k) * 512 + 256 + r];
          float4 a = c14[k * 2], b = c14[k * 2 + 1];
          FMA_8(A0, w0, a, b);
          FMA_8(A1, w1, a, b);
        }
        #pragma unroll
        for (int tt = 0; tt < 8; ++tt) {
          __hip_atomic_store(&opre1[((size_t)(t0 + tt)) * 512 + r], A0[tt],
                             __ATOMIC_RELAXED, __HIP_MEMORY_SCOPE_AGENT);
          __hip_atomic_store(&opre1[((size_t)(t0 + tt)) * 512 + 256 + r], A1[tt],
                             __ATOMIC_RELAXED, __HIP_MEMORY_SCOPE_AGENT);
        }
      }
      __syncthreads();                             // drain opre1 (vmcnt0)
      if (tid == 0)
        __hip_atomic_store(&flagC[chunk * 32], 1, __ATOMIC_RELAXED, __HIP_MEMORY_SCOPE_AGENT);
      __syncthreads();
    }
  }
}

// ---------------------------------------------------------------------------
// phaseD: parallel over t: softmaxes
// ---------------------------------------------------------------------------
__global__ void phaseD(const float* __restrict__ oh_g,
                       const float* __restrict__ Wtar, const float* __restrict__ btar,
                       const float* __restrict__ Wdir, const float* __restrict__ bdir,
                       float* __restrict__ outp) {
  __shared__ float ohl[1024];
  const int t = blockIdx.x, tid = threadIdx.x;  // 64 threads
  for (int idx = tid; idx < 1024; idx += 64) ohl[idx] = oh_g[(size_t)t * 1024 + idx];
  __syncthreads();
  const int f = tid;
  for (int e = 0; e < E_; ++e) {
    float acc = btar[f];
    const float* wr = Wtar + f * 128;
    #pragma unroll 4
    for (int k = 0; k < 128; ++k) acc = fmaf(wr[k], ohl[e * 128 + k], acc);
    float m = acc;
    #pragma unroll
    for (int off = 32; off; off >>= 1) m = fmaxf(m, __shfl_xor(m, off, 64));
    float ex = __expf(acc - m);
    float s = ex;
    #pragma unroll
    for (int off = 32; off; off >>= 1) s += __shfl_xor(s, off, 64);
    outp[((size_t)t * 8 + e) * 64 + f] = ex / s;
  }
  if (tid < 8) {
    int e = tid;
    float d0 = bdir[0], d1 = bdir[1], d2 = bdir[2];
    #pragma unroll 4
    for (int k = 0; k < 128; ++k) {
      float x = ohl[e * 128 + k];
      d0 = fmaf(Wdir[k], x, d0);
      d1 = fmaf(Wdir[128 + k], x, d1);
      d2 = fmaf(Wdir[256 + k], x, d2);
    }
    float m = fmaxf(d0, fmaxf(d1, d2));
    float x0 = __expf(d0 - m), x1 = __expf(d1 - m), x2 = __expf(d2 - m);
    float s = x0 + x1 + x2;
    float* dp = outp + (size_t)T_ * 8 * 64 + ((size_t)t * 8 + e) * 3;
    dp[0] = x0 / s; dp[1] = x1 / s; dp[2] = x2 / s;
  }
}

extern "C" void kernel_launch(void* const* d_in, const int* in_sizes, int n_in,
                              void* d_out, int out_size, void* d_ws, size_t ws_size,
                              hipStream_t stream) {
  (void)in_sizes; (void)n_in; (void)out_size; (void)ws_size;
  const float* feat   = (const float*)d_in[0];
  const float* pre_h0 = (const float*)d_in[1];
  const float* pre_c0 = (const float*)d_in[2];
  const float* out_h0 = (const float*)d_in[3];
  const float* out_c0 = (const float*)d_in[4];
  const float* Wih_p0 = (const float*)d_in[5];
  const float* Whh_p0 = (const float*)d_in[6];
  const float* b_p0   = (const float*)d_in[7];
  const float* Wih_p1 = (const float*)d_in[8];
  const float* Whh_p1 = (const float*)d_in[9];
  const float* b_p1   = (const float*)d_in[10];
  const float* Wfc    = (const float*)d_in[11];
  const float* bfc    = (const float*)d_in[12];
  const float* Wih_c0 = (const float*)d_in[13];
  const float* Whh_c0 = (const float*)d_in[14];
  const float* b_c0   = (const float*)d_in[15];
  const float* Wih_c1 = (const float*)d_in[16];
  const float* Whh_c1 = (const float*)d_in[17];
  const float* b_c1   = (const float*)d_in[18];
  const float* Wih_o  = (const float*)d_in[19];
  const float* Whh_o  = (const float*)d_in[20];
  const float* b_o    = (const float*)d_in[21];
  const float* Wtar   = (const float*)d_in[22];
  const float* btar   = (const float*)d_in[23];
  const float* Wdir   = (const float*)d_in[24];
  const float* bdir   = (const float*)d_in[25];
  float* outp = (float*)d_out;

  float* ws = (float*)d_ws;
  size_t off = 0;
  float* opre1    = ws + off; off += (size_t)T_ * 512;
  float* oh_g     = ws + off; off += (size_t)T_ * E_ * 128;
  float* wt_p0    = ws + off; off += (size_t)448 * 1024;
  float* wt_p1    = ws + off; off += (size_t)512 * 1024;
  float* wt_c0    = ws + off; off += (size_t)256 * 512;
  float* wt_c1    = ws + off; off += (size_t)256 * 512;
  float* wt_o1    = ws + off; off += (size_t)256 * 512;
  float* wt_o2    = ws + off; off += (size_t)192 * 512;
  __hip_bfloat16* opre2 = (__hip_bfloat16*)(ws + off);
  off += (size_t)T_ * E_ * 512 / 2;
  float* h1all  = ws + off; off += (size_t)T_ * 2048;
  float* h0ring = ws + off; off += (size_t)32 * 2048;   // depth 32
  float* h1ring = ws + off; off += (size_t)8 * 2048;    // depth 8
  int* flags    = (int*)(ws + off);
  int* flagsA   = flags;                                 // 64*32*32 (G1 per-step)
  int* flagB1   = flags + (size_t)64 * 32 * 32;          // 64*32*32 (G2 per-step)
  int* flagsBC  = flags + (size_t)2 * 64 * 32 * 32;      // 64*32*32 (8-step, acked)
  int* flagC    = flags + (size_t)3 * 64 * 32 * 32;      // 512*32
  int* zbase    = (int*)h0ring;   // zero span: rings + all flags

  initK<<<dim3(1024), dim3(256), 0, stream>>>(
      Wih_p0, Whh_p0, Wih_p1, Whh_p1, Wih_c0, Whh_c0, Wih_c1, Whh_c1, Wih_o,
      wt_p0, wt_p1, wt_c0, wt_c1, wt_o1, wt_o2, zbase);
  opre2K<<<dim3(T_), dim3(256), 0, stream>>>(feat, wt_o2, opre2);
  megaK<<<dim3(32 + 32 + 8 + NCON), dim3(256), 0, stream>>>(
      feat, pre_h0, pre_c0, wt_p0, wt_p1, b_p0, b_p1,
      h0ring, h1ring, h1all, flagsA, flagB1, flagsBC,
      Wfc, bfc, wt_c0, wt_c1, b_c0, b_c1, wt_o1, b_o, opre1, flagC,
      opre2, Whh_o, out_h0, out_c0, oh_g);
  phaseD<<<dim3(T_), dim3(64), 0, stream>>>(oh_g, Wtar, btar, Wdir, bdir, outp);
}

// Round 6
// 16905.496 us; speedup vs baseline: 1.4938x; 1.0652x over previous
//
#include <hip/hip_runtime.h>
#include <hip/hip_bf16.h>

// Sizes from the reference
#define T_   4096
#define E_   8
#define NCON 56    // consumer blocks (total grid = 32 + 32 + 8 + NCON = 128)

typedef unsigned long long ull;

__device__ __forceinline__ float sigm(float x)  { return 1.0f / (1.0f + __expf(-x)); }
__device__ __forceinline__ float tanh_(float x) { return 1.0f - 2.0f / (__expf(2.0f * x) + 1.0f); }

__device__ __forceinline__ ull aload64(const ull* p) {
  return __hip_atomic_load(p, __ATOMIC_RELAXED, __HIP_MEMORY_SCOPE_AGENT);
}
__device__ __forceinline__ int aload32(const int* p) {
  return __hip_atomic_load(p, __ATOMIC_RELAXED, __HIP_MEMORY_SCOPE_AGENT);
}
__device__ __forceinline__ float aloadf(const float* p) {
  return __hip_atomic_load(p, __ATOMIC_RELAXED, __HIP_MEMORY_SCOPE_AGENT);
}
// barrier draining LDS (lgkm) but not vector memory
__device__ __forceinline__ void lbar() {
  asm volatile("s_waitcnt lgkmcnt(0)\n\ts_barrier" ::: "memory");
}

#define FMA_8(ACC, W, VA, VB)                                   \
  ACC[0] = fmaf((W), (VA).x, ACC[0]); ACC[1] = fmaf((W), (VA).y, ACC[1]); \
  ACC[2] = fmaf((W), (VA).z, ACC[2]); ACC[3] = fmaf((W), (VA).w, ACC[3]); \
  ACC[4] = fmaf((W), (VB).x, ACC[4]); ACC[5] = fmaf((W), (VB).y, ACC[5]); \
  ACC[6] = fmaf((W), (VB).z, ACC[6]); ACC[7] = fmaf((W), (VB).w, ACC[7]);

// ---------------------------------------------------------------------------
// initK: K-major packed weight copies + zero rings / flags.
// ---------------------------------------------------------------------------
__global__ void initK(const float* __restrict__ Wih_p0, const float* __restrict__ Whh_p0,
                      const float* __restrict__ Wih_p1, const float* __restrict__ Whh_p1,
                      const float* __restrict__ Wih_c0, const float* __restrict__ Whh_c0,
                      const float* __restrict__ Wih_c1, const float* __restrict__ Whh_c1,
                      const float* __restrict__ Wih_o,
                      float* wt_p0, float* wt_p1, float* wt_c0, float* wt_c1,
                      float* wt_o1, float* wt_o2, int* zbase) {
  const int NW = 458752 + 524288 + 131072 + 131072 + 131072 + 98304;
  // zero: h0ring 65536 + h1ring 16384 + flagsA 65536 + flagB1 65536
  //       + flagsBC 65536 + flagC 16384
  const int NZ = 65536 + 16384 + 65536 + 65536 + 65536 + 16384;
  const int NTOT = NW + NZ;
  const int gsz = gridDim.x * blockDim.x;
  for (int i = blockIdx.x * blockDim.x + threadIdx.x; i < NTOT; i += gsz) {
    int idx = i;
    if (idx < 458752) { int k = idx >> 10, c = idx & 1023;
      int wg = c >> 5, r5 = c & 31, gate = r5 >> 3, jl = r5 & 7;
      int col = gate * 256 + wg * 8 + jl;
      wt_p0[idx] = (k < 192) ? Wih_p0[col * 192 + k] : Whh_p0[col * 256 + (k - 192)]; continue; }
    idx -= 458752;
    if (idx < 524288) { int k = idx >> 10, c = idx & 1023;
      int wg = c >> 5, r5 = c & 31, gate = r5 >> 3, jl = r5 & 7;
      int col = gate * 256 + wg * 8 + jl;
      wt_p1[idx] = (k < 256) ? Wih_p1[col * 256 + k] : Whh_p1[col * 256 + (k - 256)]; continue; }
    idx -= 524288;
    if (idx < 131072) { int k = idx >> 9, r = idx & 511;
      wt_c0[idx] = (k < 128) ? Wih_c0[r * 128 + k] : Whh_c0[r * 128 + (k - 128)]; continue; }
    idx -= 131072;
    if (idx < 131072) { int k = idx >> 9, r = idx & 511;
      wt_c1[idx] = (k < 128) ? Wih_c1[r * 128 + k] : Whh_c1[r * 128 + (k - 128)]; continue; }
    idx -= 131072;
    if (idx < 131072) { int k = idx >> 9, r = idx & 511;
      wt_o1[idx] = Wih_o[r * 448 + k]; continue; }
    idx -= 131072;
    if (idx < 98304) { int k = idx >> 9, r = idx & 511;
      wt_o2[idx] = Wih_o[r * 448 + 256 + k]; continue; }
    idx -= 98304;
    zbase[idx] = 0;
  }
}

// ---------------------------------------------------------------------------
// opre2K: parallel over t. opre2[t][e][512] = Wih_o[:,256:448] @ x(t,e)  (bf16)
// ---------------------------------------------------------------------------
__global__ void opre2K(const float* __restrict__ feat, const float* __restrict__ wt_o2,
                       __hip_bfloat16* __restrict__ opre2) {
  __shared__ float xb[192 * 8];
  const int t = blockIdx.x, tid = threadIdx.x;
  const float* ft = feat + (size_t)t * 640;
  for (int idx = tid; idx < 192 * 8; idx += 256) {
    int k = idx >> 3, e = idx & 7;
    xb[idx] = (k < 128) ? ft[k] : ft[128 + e * 64 + (k - 128)];
  }
  __syncthreads();
  const int r = tid;
  float A0[8] = {0,0,0,0,0,0,0,0};
  float A1[8] = {0,0,0,0,0,0,0,0};
  const float4* x4 = (const float4*)xb;
  #pragma unroll 2
  for (int k = 0; k < 192; ++k) {
    float w0 = wt_o2[k * 512 + r];
    float w1 = wt_o2[k * 512 + 256 + r];
    float4 a = x4[k * 2], b = x4[k * 2 + 1];
    FMA_8(A0, w0, a, b);
    FMA_8(A1, w1, a, b);
  }
  #pragma unroll
  for (int e = 0; e < 8; ++e) {
    opre2[((size_t)t * 8 + e) * 512 + r]       = __float2bfloat16(A0[e]);
    opre2[((size_t)t * 8 + e) * 512 + 256 + r] = __float2bfloat16(A1[e]);
  }
}

// ---------------------------------------------------------------------------
// comm cell (unchanged math)
// ---------------------------------------------------------------------------
__device__ __forceinline__ void comm_cell(
    const float* __restrict__ wt, const float* __restrict__ bias,
    const float* xin, float* hL, float* cL, float* glb, float* hout,
    float alpha, int tid) {
  const int r = tid;
  float A0[8] = {0,0,0,0,0,0,0,0};
  float A1[8] = {0,0,0,0,0,0,0,0};
  const float4* x4 = (const float4*)xin;
  #pragma unroll 2
  for (int k = 0; k < 128; ++k) {
    float w0 = wt[k * 512 + r];
    float w1 = wt[k * 512 + 256 + r];
    float4 a = x4[k * 2], b = x4[k * 2 + 1];
    FMA_8(A0, w0, a, b);
    FMA_8(A1, w1, a, b);
  }
  const float4* h4 = (const float4*)hL;
  #pragma unroll 2
  for (int k = 0; k < 128; ++k) {
    float w0 = wt[(128 + k) * 512 + r];
    float w1 = wt[(128 + k) * 512 + 256 + r];
    float4 a = h4[k * 2], b = h4[k * 2 + 1];
    FMA_8(A0, w0, a, b);
    FMA_8(A1, w1, a, b);
  }
  {
    float4* g4 = (float4*)glb;
    g4[r * 2]             = make_float4(A0[0], A0[1], A0[2], A0[3]);
    g4[r * 2 + 1]         = make_float4(A0[4], A0[5], A0[6], A0[7]);
    g4[(256 + r) * 2]     = make_float4(A1[0], A1[1], A1[2], A1[3]);
    g4[(256 + r) * 2 + 1] = make_float4(A1[4], A1[5], A1[6], A1[7]);
  }
  __syncthreads();
  for (int idx = tid; idx < 1024; idx += 256) {
    int jj = idx >> 3, tt = idx & 7;
    float gi = glb[jj * 8 + tt]         + bias[jj];
    float gf = glb[(128 + jj) * 8 + tt] + bias[128 + jj];
    float gg = glb[(256 + jj) * 8 + tt] + bias[256 + jj];
    float go = glb[(384 + jj) * 8 + tt] + bias[384 + jj];
    float cold = cL[idx], hold = hL[idx];
    float c2 = sigm(gf) * cold + sigm(gi) * tanh_(gg);
    float h2 = sigm(go) * tanh_(c2);
    float hb = fmaf(alpha, h2 - hold, hold);
    float cb = fmaf(alpha, c2 - cold, cold);
    hL[idx] = hb; cL[idx] = cb;
    if (hout) hout[idx] = hb;
  }
  __syncthreads();
}

// ---------------------------------------------------------------------------
// MEGA kernel: 128 blocks, 256 thr, 155648 B LDS => 1 block/CU; only half the
// CUs carry blocks at all => power/clock headroom for the latency-bound
// recurrence + far less background flag-poll traffic in L3.
// Protocol = R1 (acked per-step flag, load-once from ring), with h1all moved
// AFTER the per-step flag (its HBM-backed store ack no longer delays peers);
// the 8-step flagsBC ack drains the h1all backlog for consumers.
//   blocks 0-31  : G1 layer0; h0ring depth 32, free-runs (lag-24 backpressure
//                  on 8-step flagsBC, sleep 16)
//   blocks 32-63 : G2 layer1; h1ring depth 8; prefetch-polls h0(t+2)
//   blocks 64-71 : phaseC per-e output LSTM
//   blocks 72-   : consumers: fused fc+comm per 8-t chunk (flagsBC, sleep 64)
// ---------------------------------------------------------------------------
__launch_bounds__(256, 1)
__global__ void megaK(const float* __restrict__ feat,
                      const float* __restrict__ pre_h0, const float* __restrict__ pre_c0,
                      const float* __restrict__ wt_p0, const float* __restrict__ wt_p1,
                      const float* __restrict__ b_p0, const float* __restrict__ b_p1,
                      float* __restrict__ h0ring, float* __restrict__ h1ring,
                      float* __restrict__ h1all,
                      int* __restrict__ flagsA, int* __restrict__ flagB1,
                      int* __restrict__ flagsBC,
                      const float* __restrict__ Wfc, const float* __restrict__ bfc,
                      const float* __restrict__ wt_c0, const float* __restrict__ wt_c1,
                      const float* __restrict__ b_c0, const float* __restrict__ b_c1,
                      const float* __restrict__ wt_o1, const float* __restrict__ b_o,
                      float* __restrict__ opre1, int* __restrict__ flagC,
                      const __hip_bfloat16* __restrict__ opre2,
                      const float* __restrict__ Whh_o, const float* __restrict__ out_h0,
                      const float* __restrict__ out_c0, float* __restrict__ oh_g) {
  __shared__ float lds[38912];   // 155,648 B
  const int wg = blockIdx.x, tid = threadIdx.x;

  if (wg < 32) {
    // ============================ G1: layer0 (32 blocks) ============================
    float* wl   = lds;            // 14336: weights [k][32], k<448
    float* xbuf = lds + 14336;    // 1536
    float* hsf  = lds + 15872;    // 2048
    float* gl   = lds + 17920;    // 2048 partials
    const int r5 = tid & 31, kq = tid >> 5;
    for (int idx = tid; idx < 14336; idx += 256)
      wl[idx] = wt_p0[(size_t)(idx >> 5) * 1024 + wg * 32 + (idx & 31)];
    float creg = 0.f, bi = 0.f, bff = 0.f, bg = 0.f, bo = 0.f;
    if (tid < 64) {
      const int jl = tid >> 3, e = tid & 7, j = wg * 8 + jl;
      creg = pre_c0[(e * 2 + 0) * 256 + j];
      bi = b_p0[j]; bff = b_p0[256 + j]; bg = b_p0[512 + j]; bo = b_p0[768 + j];
    }
    for (int idx = tid; idx < 2048; idx += 256) {
      int k = idx >> 3, e = idx & 7;
      hsf[idx] = pre_h0[(e * 2 + 0) * 256 + k];
    }
    for (int idx = tid; idx < 1536; idx += 256) {
      int k = idx >> 3, e = idx & 7;
      xbuf[idx] = (k < 128) ? feat[k] : feat[128 + e * 64 + (k - 128)];
    }
    __syncthreads();
    float Ax[8] = {0,0,0,0,0,0,0,0};
    {
      const float4* x4 = (const float4*)xbuf;
      #pragma unroll
      for (int k = kq * 24; k < kq * 24 + 24; ++k) {
        float w = wl[k * 32 + r5];
        float4 a = x4[k * 2], b = x4[k * 2 + 1];
        FMA_8(Ax, w, a, b);
      }
    }
    for (int t = 0; t < T_; ++t) {
      float px[6];
      if (t + 1 < T_) {
        const float* ft1 = feat + (size_t)(t + 1) * 640;
        #pragma unroll
        for (int i = 0; i < 6; ++i) {
          int idx = tid + i * 256; int k = idx >> 3, e = idx & 7;
          px[i] = (k < 128) ? ft1[k] : ft1[128 + e * 64 + (k - 128)];
        }
      }
      float A[8];
      #pragma unroll
      for (int i = 0; i < 8; ++i) A[i] = Ax[i];
      {
        const float4* h4 = (const float4*)hsf;
        #pragma unroll
        for (int k2 = 0; k2 < 32; ++k2) {
          const int k = kq * 32 + k2;
          float w = wl[(192 + k) * 32 + r5];
          float4 a = h4[k * 2], b = h4[k * 2 + 1];
          FMA_8(A, w, a, b);
        }
      }
      {
        float4* g4 = (float4*)gl;
        g4[(kq * 32 + r5) * 2]     = make_float4(A[0], A[1], A[2], A[3]);
        g4[(kq * 32 + r5) * 2 + 1] = make_float4(A[4], A[5], A[6], A[7]);
      }
      if (t >= 24 && tid >= 224) {                 // back-pressure, lag 24 (8-step gran)
        const int t2 = (t - 24) | 7;
        const int* fp = flagsBC + ((size_t)(t2 & 63) * 32 + (tid - 224)) * 32;
        while (aload32(fp) < t2 + 1) __builtin_amdgcn_s_sleep(16);
      }
      lbar();                                      // S1
      if (tid < 64) {
        float s0 = 0.f, s1 = 0.f, s2 = 0.f, s3 = 0.f;
        #pragma unroll
        for (int q = 0; q < 8; ++q) {
          s0 += gl[q * 256 + tid];       s1 += gl[q * 256 + 64 + tid];
          s2 += gl[q * 256 + 128 + tid]; s3 += gl[q * 256 + 192 + tid];
        }
        float c2 = sigm(s1 + bff) * creg + sigm(s0 + bi) * tanh_(s2 + bg);
        float h2 = sigm(s3 + bo) * tanh_(c2);
        creg = c2;
        __hip_atomic_store(&h0ring[(size_t)(t & 31) * 2048 + wg * 64 + tid], h2,
                           __ATOMIC_RELAXED, __HIP_MEMORY_SCOPE_AGENT);
        asm volatile("s_waitcnt vmcnt(0)" ::: "memory");   // ring-store ack
        if (tid == 0)
          __hip_atomic_store(&flagsA[((size_t)(t & 63) * 32 + wg) * 32], t + 1,
                             __ATOMIC_RELAXED, __HIP_MEMORY_SCOPE_AGENT);
      }
      if (t + 1 >= T_) break;
      #pragma unroll
      for (int i = 0; i < 6; ++i) xbuf[tid + i * 256] = px[i];
      if (tid >= 64 && tid < 96) {                 // wave1 detects h0(t) flags
        const int* fp = flagsA + ((size_t)(t & 63) * 32 + (tid - 64)) * 32;
        while (aload32(fp) < t + 1) __builtin_amdgcn_s_sleep(1);
      }
      lbar();                                      // S3: xbuf staged + flags seen
      ull v[4];
      {
        const ull* s8 = (const ull*)(h0ring + (size_t)(t & 31) * 2048);
        #pragma unroll
        for (int i = 0; i < 4; ++i) v[i] = aload64(s8 + tid * 4 + i);
      }
      #pragma unroll
      for (int i = 0; i < 8; ++i) Ax[i] = 0.f;
      {                                            // x-matvec overlaps the ring loads
        const float4* x4 = (const float4*)xbuf;
        #pragma unroll
        for (int k = kq * 24; k < kq * 24 + 24; ++k) {
          float w = wl[k * 32 + r5];
          float4 a = x4[k * 2], b = x4[k * 2 + 1];
          FMA_8(Ax, w, a, b);
        }
      }
      {
        ull* d8 = (ull*)hsf;
        #pragma unroll
        for (int i = 0; i < 4; ++i) d8[tid * 4 + i] = v[i];
      }
      lbar();                                      // S4
    }
  } else if (wg < 64) {
    // ============================ G2: layer1 (32 blocks) ============================
    const int wgl = wg - 32;
    float* wl  = lds;             // 16384: weights [k][32], k<512
    float* xh0 = lds + 16384;     // 2048
    float* hsf = lds + 18432;     // 2048
    float* gl  = lds + 20480;     // 2048
    const int r5 = tid & 31, kq = tid >> 5;
    for (int idx = tid; idx < 16384; idx += 256)
      wl[idx] = wt_p1[(size_t)(idx >> 5) * 1024 + wgl * 32 + (idx & 31)];
    float creg = 0.f, bi = 0.f, bff = 0.f, bg = 0.f, bo = 0.f;
    if (tid < 64) {
      const int jl = tid >> 3, e = tid & 7, j = wgl * 8 + jl;
      creg = pre_c0[(e * 2 + 1) * 256 + j];
      bi = b_p1[j]; bff = b_p1[256 + j]; bg = b_p1[512 + j]; bo = b_p1[768 + j];
    }
    for (int idx = tid; idx < 2048; idx += 256) {
      int k = idx >> 3, e = idx & 7;
      hsf[idx] = pre_h0[(e * 2 + 1) * 256 + k];
    }
    __syncthreads();
    // prologue: wait for h0(0) and h0(1)
    if (tid >= 64 && tid < 128) {
      const int lane = tid - 64;
      const int slot = lane >> 5, b = lane & 31;
      const int* fp = flagsA + ((size_t)slot * 32 + b) * 32;
      while (aload32(fp) < slot + 1) __builtin_amdgcn_s_sleep(1);
    }
    __syncthreads();
    ull v0[4];
    {
      const ull* s8 = (const ull*)h0ring;          // slot 0 = h0(0)
      #pragma unroll
      for (int i = 0; i < 4; ++i) v0[i] = aload64(s8 + tid * 4 + i);
    }
    {
      ull* d8 = (ull*)xh0;
      #pragma unroll
      for (int i = 0; i < 4; ++i) d8[tid * 4 + i] = v0[i];
    }
    lbar();
    float Ax[8] = {0,0,0,0,0,0,0,0};
    {
      const float4* x4 = (const float4*)xh0;
      #pragma unroll
      for (int k = kq * 32; k < kq * 32 + 32; ++k) {
        float w = wl[k * 32 + r5];
        float4 a = x4[k * 2], b = x4[k * 2 + 1];
        FMA_8(Ax, w, a, b);
      }
    }
    {
      const ull* s8 = (const ull*)(h0ring + 2048); // slot 1 = h0(1), prefetch
      #pragma unroll
      for (int i = 0; i < 4; ++i) v0[i] = aload64(s8 + tid * 4 + i);
    }
    for (int t = 0; t < T_; ++t) {
      float A[8];
      #pragma unroll
      for (int i = 0; i < 8; ++i) A[i] = Ax[i];
      {
        const float4* h4 = (const float4*)hsf;
        #pragma unroll
        for (int k2 = 0; k2 < 32; ++k2) {
          const int k = kq * 32 + k2;
          float w = wl[(256 + k) * 32 + r5];
          float4 a = h4[k * 2], b = h4[k * 2 + 1];
          FMA_8(A, w, a, b);
        }
      }
      {
        float4* g4 = (float4*)gl;
        g4[(kq * 32 + r5) * 2]     = make_float4(A[0], A[1], A[2], A[3]);
        g4[(kq * 32 + r5) * 2 + 1] = make_float4(A[4], A[5], A[6], A[7]);
      }
      lbar();                                      // S1
      if (tid < 64) {
        float s0 = 0.f, s1 = 0.f, s2 = 0.f, s3 = 0.f;
        #pragma unroll
        for (int q = 0; q < 8; ++q) {
          s0 += gl[q * 256 + tid];       s1 += gl[q * 256 + 64 + tid];
          s2 += gl[q * 256 + 128 + tid]; s3 += gl[q * 256 + 192 + tid];
        }
        float c2 = sigm(s1 + bff) * creg + sigm(s0 + bi) * tanh_(s2 + bg);
        float h2 = sigm(s3 + bo) * tanh_(c2);
        creg = c2;
        __hip_atomic_store(&h1ring[(size_t)(t & 7) * 2048 + wgl * 64 + tid], h2,
                           __ATOMIC_RELAXED, __HIP_MEMORY_SCOPE_AGENT);
        asm volatile("s_waitcnt vmcnt(0)" ::: "memory");   // ring-store ack ONLY
        if (tid == 0)
          __hip_atomic_store(&flagB1[((size_t)(t & 63) * 32 + wgl) * 32], t + 1,
                             __ATOMIC_RELAXED, __HIP_MEMORY_SCOPE_AGENT);
        // h1all AFTER the flag: its (slow, HBM-backed) ack no longer delays peers
        __hip_atomic_store(&h1all[(size_t)t * 2048 + wgl * 64 + tid], h2,
                           __ATOMIC_RELAXED, __HIP_MEMORY_SCOPE_AGENT);
        if ((t & 7) == 7) {                        // acked consumer-facing flag
          asm volatile("s_waitcnt vmcnt(0)" ::: "memory");  // drains h1all backlog
          if (tid == 0)
            __hip_atomic_store(&flagsBC[((size_t)(t & 63) * 32 + wgl) * 32], t + 1,
                               __ATOMIC_RELAXED, __HIP_MEMORY_SCOPE_AGENT);
        }
      }
      if (t + 1 >= T_) break;
      // wave1: detect own-group h1(t) + prefetch-poll h0(t+2)
      if (tid >= 64 && tid < 128) {
        const int lane = tid - 64;
        if (lane < 32) {
          const int* fp = flagB1 + ((size_t)(t & 63) * 32 + lane) * 32;
          while (aload32(fp) < t + 1) __builtin_amdgcn_s_sleep(1);
        } else if (t + 2 < T_) {
          const int* fp = flagsA + ((size_t)((t + 2) & 63) * 32 + (lane - 32)) * 32;
          while (aload32(fp) < t + 3) __builtin_amdgcn_s_sleep(1);
        }
      }
      lbar();                                      // S2
      ull v1[4];
      {                                            // issue h1(t) loads (in flight)
        const ull* s8 = (const ull*)(h1ring + (size_t)(t & 7) * 2048);
        #pragma unroll
        for (int i = 0; i < 4; ++i) v1[i] = aload64(s8 + tid * 4 + i);
      }
      {                                            // stage xh0 = h0(t+1) from regs
        ull* d8 = (ull*)xh0;
        #pragma unroll
        for (int i = 0; i < 4; ++i) d8[tid * 4 + i] = v0[i];
      }
      lbar();                                      // S3: xh0 staged (v1 still in flight)
      if (t + 2 < T_) {                            // prefetch h0(t+2) for next iter
        const ull* s8 = (const ull*)(h0ring + (size_t)((t + 2) & 31) * 2048);
        #pragma unroll
        for (int i = 0; i < 4; ++i) v0[i] = aload64(s8 + tid * 4 + i);
      }
      #pragma unroll
      for (int i = 0; i < 8; ++i) Ax[i] = 0.f;
      {                                            // x-part: overlaps v1 latency
        const float4* x4 = (const float4*)xh0;
        #pragma unroll
        for (int k = kq * 32; k < kq * 32 + 32; ++k) {
          float w = wl[k * 32 + r5];
          float4 a = x4[k * 2], b = x4[k * 2 + 1];
          FMA_8(Ax, w, a, b);
        }
      }
      {
        ull* d8 = (ull*)hsf;
        #pragma unroll
        for (int i = 0; i < 4; ++i) d8[tid * 4 + i] = v1[i];
      }
      lbar();                                      // S4
    }
  } else if (wg < 72) {
    // ============================ phaseC (per e) ============================
    const int e = wg - 64;
    float* wlds = lds;            // [k][256] rows 256-511: 32768 floats
    float* ohl  = lds + 32768;    // 128
    float* gl   = lds + 32896;    // 512
    for (int idx = tid; idx < 32768; idx += 256) {
      int k = idx >> 8, rr = idx & 255;
      wlds[idx] = Whh_o[(256 + rr) * 128 + k];
    }
    float w[128];
    #pragma unroll
    for (int k = 0; k < 128; ++k) w[k] = Whh_o[tid * 128 + k];
    if (tid < 128) ohl[tid] = out_h0[e * 128 + tid];
    float creg = (tid < 128) ? out_c0[e * 128 + tid] : 0.f;
    __syncthreads();
    if (tid == 0) { while (aload32(&flagC[0]) == 0) __builtin_amdgcn_s_sleep(4); }
    __syncthreads();
    const int r0 = tid, r1 = tid + 256;
    float pa = aloadf(&opre1[r0]), pb = aloadf(&opre1[r1]);
    float qa = __bfloat162float(opre2[(size_t)e * 512 + r0]);
    float qb = __bfloat162float(opre2[(size_t)e * 512 + r1]);
    float na = aloadf(&opre1[512 + r0]), nb = aloadf(&opre1[512 + r1]);
    float ma = __bfloat162float(opre2[(size_t)(8 + e) * 512 + r0]);
    float mb = __bfloat162float(opre2[(size_t)(8 + e) * 512 + r1]);
    for (int t = 0; t < T_; ++t) {
      float a0 = pa + qa, a1 = pb + qb;
      pa = na; pb = nb; qa = ma; qb = mb;
      if ((t & 7) == 6 && t + 2 < T_) {            // next chunk ready?
        if (tid == 0) { while (aload32(&flagC[((t + 2) >> 3) * 32]) == 0) __builtin_amdgcn_s_sleep(4); }
        __syncthreads();
      }
      if (t + 2 < T_) {
        na = aloadf(&opre1[(size_t)(t + 2) * 512 + r0]);
        nb = aloadf(&opre1[(size_t)(t + 2) * 512 + r1]);
        ma = __bfloat162float(opre2[((size_t)(t + 2) * 8 + e) * 512 + r0]);
        mb = __bfloat162float(opre2[((size_t)(t + 2) * 8 + e) * 512 + r1]);
      }
      const float4* o4 = (const float4*)ohl;
      #pragma unroll
      for (int kk = 0; kk < 32; ++kk) {
        float4 x = o4[kk];
        a0 = fmaf(w[kk * 4 + 0], x.x, a0); a0 = fmaf(w[kk * 4 + 1], x.y, a0);
        a0 = fmaf(w[kk * 4 + 2], x.z, a0); a0 = fmaf(w[kk * 4 + 3], x.w, a0);
        a1 = fmaf(wlds[(kk * 4 + 0) * 256 + tid], x.x, a1);
        a1 = fmaf(wlds[(kk * 4 + 1) * 256 + tid], x.y, a1);
        a1 = fmaf(wlds[(kk * 4 + 2) * 256 + tid], x.z, a1);
        a1 = fmaf(wlds[(kk * 4 + 3) * 256 + tid], x.w, a1);
      }
      gl[r0] = a0; gl[r1] = a1;
      __syncthreads();
      if (tid < 128) {
        float gi = gl[tid], gf = gl[128 + tid], gg = gl[256 + tid], go = gl[384 + tid];
        float c2 = sigm(gf) * creg + sigm(gi) * tanh_(gg);
        float h2 = sigm(go) * tanh_(c2);
        creg = c2;
        ohl[tid] = h2;
        oh_g[(size_t)t * 1024 + e * 128 + tid] = h2;
      }
      __syncthreads();
    }
  } else {
    // ==================== consumers: fused fc + comm ====================
    const int cb = wg - 72;
    float* h1c    = lds;          // 16384
    float* polAll = lds + 16384;  // 8192
    float* ch0 = lds + 24576; float* cc0 = lds + 25600;
    float* ch1 = lds + 26624; float* cc1 = lds + 27648;
    float* h0b = lds + 28672;     // 1024
    float* glb = lds + 29696;     // 4096
    for (int chunk = cb; chunk < 512; chunk += NCON) {
      const int t0 = chunk * 8;
      if (tid < 32) {
        const int* fp = flagsBC + ((size_t)((t0 + 7) & 63) * 32 + tid) * 32;
        while (aload32(fp) < t0 + 8) __builtin_amdgcn_s_sleep(64);
      }
      __syncthreads();
      {
        const ull* src = (const ull*)(h1all + (size_t)t0 * 2048);
        ull* dst = (ull*)h1c;
        for (int i = tid; i < 8192; i += 256) dst[i] = aload64(src + i);
      }
      __syncthreads();
      {  // fc for 8 ts -> polAll[e][c*8+tt]
        const int c = tid >> 1, half = tid & 1;
        const float bv = bfc[c];
        const float* wrow = Wfc + c * 256;
        for (int tt = 0; tt < 8; ++tt) {
          float a0 = bv, a1 = bv, a2 = bv, a3 = bv;
          const float4* h4 = (const float4*)(h1c + tt * 2048);
          #pragma unroll 4
          for (int k = 0; k < 256; ++k) {
            float wv = wrow[k];
            float4 x = h4[k * 2 + half];
            a0 = fmaf(wv, x.x, a0); a1 = fmaf(wv, x.y, a1);
            a2 = fmaf(wv, x.z, a2); a3 = fmaf(wv, x.w, a3);
          }
          float vv[4] = {a0, a1, a2, a3};
          #pragma unroll
          for (int i = 0; i < 4; ++i) {
            float v = vv[i];
            v = (v > 0.f) ? v : 0.05f * v;
            polAll[(half * 4 + i) * 1024 + c * 8 + tt] = v;
          }
        }
      }
      for (int idx = tid; idx < 1024; idx += 256) { ch0[idx]=0.f; cc0[idx]=0.f; ch1[idx]=0.f; cc1[idx]=0.f; }
      __syncthreads();
      float alpha = 1.0f;
      for (int rd = 0; rd < 3; ++rd) {
        for (int e = 0; e < E_; ++e) {
          comm_cell(wt_c0, b_c0, polAll + e * 1024, ch0, cc0, glb, h0b, alpha, tid);
          comm_cell(wt_c1, b_c1, h0b, ch1, cc1, glb, nullptr, alpha, tid);
        }
        alpha *= 0.333f;
      }
      {  // opre1 epilogue (atomic stores for intra-kernel visibility)
        const int r = tid;
        float A0[8], A1[8];
        #pragma unroll
        for (int tt = 0; tt < 8; ++tt) { A0[tt] = b_o[r]; A1[tt] = b_o[256 + r]; }
        const float4* c04 = (const float4*)cc0;
        const float4* c14 = (const float4*)cc1;
        #pragma unroll 2
        for (int k = 0; k < 128; ++k) {
          float w0 = wt_o1[k * 512 + r], w1 = wt_o1[k * 512 + 256 + r];
          float4 a = c04[k * 2], b = c04[k * 2 + 1];
          FMA_8(A0, w0, a, b);
          FMA_8(A1, w1, a, b);
        }
        #pragma unroll 2
        for (int k = 0; k < 128; ++k) {
          float w0 = wt_o1[(128 + k) * 512 + r], w1 = wt_o1[(128 + k) * 512 + 256 + r];
          float4 a = c14[k * 2], b = c14[k * 2 + 1];
          FMA_8(A0, w0, a, b);
          FMA_8(A1, w1, a, b);
        }
        #pragma unroll
        for (int tt = 0; tt < 8; ++tt) {
          __hip_atomic_store(&opre1[((size_t)(t0 + tt)) * 512 + r], A0[tt],
                             __ATOMIC_RELAXED, __HIP_MEMORY_SCOPE_AGENT);
          __hip_atomic_store(&opre1[((size_t)(t0 + tt)) * 512 + 256 + r], A1[tt],
                             __ATOMIC_RELAXED, __HIP_MEMORY_SCOPE_AGENT);
        }
      }
      __syncthreads();                             // drain opre1 (vmcnt0)
      if (tid == 0)
        __hip_atomic_store(&flagC[chunk * 32], 1, __ATOMIC_RELAXED, __HIP_MEMORY_SCOPE_AGENT);
      __syncthreads();
    }
  }
}

// ---------------------------------------------------------------------------
// phaseD: parallel over t: softmaxes
// ---------------------------------------------------------------------------
__global__ void phaseD(const float* __restrict__ oh_g,
                       const float* __restrict__ Wtar, const float* __restrict__ btar,
                       const float* __restrict__ Wdir, const float* __restrict__ bdir,
                       float* __restrict__ outp) {
  __shared__ float ohl[1024];
  const int t = blockIdx.x, tid = threadIdx.x;  // 64 threads
  for (int idx = tid; idx < 1024; idx += 64) ohl[idx] = oh_g[(size_t)t * 1024 + idx];
  __syncthreads();
  const int f = tid;
  for (int e = 0; e < E_; ++e) {
    float acc = btar[f];
    const float* wr = Wtar + f * 128;
    #pragma unroll 4
    for (int k = 0; k < 128; ++k) acc = fmaf(wr[k], ohl[e * 128 + k], acc);
    float m = acc;
    #pragma unroll
    for (int off = 32; off; off >>= 1) m = fmaxf(m, __shfl_xor(m, off, 64));
    float ex = __expf(acc - m);
    float s = ex;
    #pragma unroll
    for (int off = 32; off; off >>= 1) s += __shfl_xor(s, off, 64);
    outp[((size_t)t * 8 + e) * 64 + f] = ex / s;
  }
  if (tid < 8) {
    int e = tid;
    float d0 = bdir[0], d1 = bdir[1], d2 = bdir[2];
    #pragma unroll 4
    for (int k = 0; k < 128; ++k) {
      float x = ohl[e * 128 + k];
      d0 = fmaf(Wdir[k], x, d0);
      d1 = fmaf(Wdir[128 + k], x, d1);
      d2 = fmaf(Wdir[256 + k], x, d2);
    }
    float m = fmaxf(d0, fmaxf(d1, d2));
    float x0 = __expf(d0 - m), x1 = __expf(d1 - m), x2 = __expf(d2 - m);
    float s = x0 + x1 + x2;
    float* dp = outp + (size_t)T_ * 8 * 64 + ((size_t)t * 8 + e) * 3;
    dp[0] = x0 / s; dp[1] = x1 / s; dp[2] = x2 / s;
  }
}

extern "C" void kernel_launch(void* const* d_in, const int* in_sizes, int n_in,
                              void* d_out, int out_size, void* d_ws, size_t ws_size,
                              hipStream_t stream) {
  (void)in_sizes; (void)n_in; (void)out_size; (void)ws_size;
  const float* feat   = (const float*)d_in[0];
  const float* pre_h0 = (const float*)d_in[1];
  const float* pre_c0 = (const float*)d_in[2];
  const float* out_h0 = (const float*)d_in[3];
  const float* out_c0 = (const float*)d_in[4];
  const float* Wih_p0 = (const float*)d_in[5];
  const float* Whh_p0 = (const float*)d_in[6];
  const float* b_p0   = (const float*)d_in[7];
  const float* Wih_p1 = (const float*)d_in[8];
  const float* Whh_p1 = (const float*)d_in[9];
  const float* b_p1   = (const float*)d_in[10];
  const float* Wfc    = (const float*)d_in[11];
  const float* bfc    = (const float*)d_in[12];
  const float* Wih_c0 = (const float*)d_in[13];
  const float* Whh_c0 = (const float*)d_in[14];
  const float* b_c0   = (const float*)d_in[15];
  const float* Wih_c1 = (const float*)d_in[16];
  const float* Whh_c1 = (const float*)d_in[17];
  const float* b_c1   = (const float*)d_in[18];
  const float* Wih_o  = (const float*)d_in[19];
  const float* Whh_o  = (const float*)d_in[20];
  const float* b_o    = (const float*)d_in[21];
  const float* Wtar   = (const float*)d_in[22];
  const float* btar   = (const float*)d_in[23];
  const float* Wdir   = (const float*)d_in[24];
  const float* bdir   = (const float*)d_in[25];
  float* outp = (float*)d_out;

  float* ws = (float*)d_ws;
  size_t off = 0;
  float* opre1    = ws + off; off += (size_t)T_ * 512;
  float* oh_g     = ws + off; off += (size_t)T_ * E_ * 128;
  float* wt_p0    = ws + off; off += (size_t)448 * 1024;
  float* wt_p1    = ws + off; off += (size_t)512 * 1024;
  float* wt_c0    = ws + off; off += (size_t)256 * 512;
  float* wt_c1    = ws + off; off += (size_t)256 * 512;
  float* wt_o1    = ws + off; off += (size_t)256 * 512;
  float* wt_o2    = ws + off; off += (size_t)192 * 512;
  __hip_bfloat16* opre2 = (__hip_bfloat16*)(ws + off);
  off += (size_t)T_ * E_ * 512 / 2;
  float* h1all  = ws + off; off += (size_t)T_ * 2048;
  float* h0ring = ws + off; off += (size_t)32 * 2048;   // depth 32
  float* h1ring = ws + off; off += (size_t)8 * 2048;    // depth 8
  int* flags    = (int*)(ws + off);
  int* flagsA   = flags;                                 // 64*32*32 (G1 per-step)
  int* flagB1   = flags + (size_t)64 * 32 * 32;          // 64*32*32 (G2 per-step)
  int* flagsBC  = flags + (size_t)2 * 64 * 32 * 32;      // 64*32*32 (8-step, acked)
  int* flagC    = flags + (size_t)3 * 64 * 32 * 32;      // 512*32
  int* zbase    = (int*)h0ring;   // zero span: rings + all flags

  initK<<<dim3(1024), dim3(256), 0, stream>>>(
      Wih_p0, Whh_p0, Wih_p1, Whh_p1, Wih_c0, Whh_c0, Wih_c1, Whh_c1, Wih_o,
      wt_p0, wt_p1, wt_c0, wt_c1, wt_o1, wt_o2, zbase);
  opre2K<<<dim3(T_), dim3(256), 0, stream>>>(feat, wt_o2, opre2);
  megaK<<<dim3(32 + 32 + 8 + NCON), dim3(256), 0, stream>>>(
      feat, pre_h0, pre_c0, wt_p0, wt_p1, b_p0, b_p1,
      h0ring, h1ring, h1all, flagsA, flagB1, flagsBC,
      Wfc, bfc, wt_c0, wt_c1, b_c0, b_c1, wt_o1, b_o, opre1, flagC,
      opre2, Whh_o, out_h0, out_c0, oh_g);
  phaseD<<<dim3(T_), dim3(64), 0, stream>>>(oh_g, Wtar, btar, Wdir, bdir, outp);
}

// Round 7
// 15784.694 us; speedup vs baseline: 1.5999x; 1.0710x over previous
//
#include <hip/hip_runtime.h>
#include <hip/hip_bf16.h>

// Sizes from the reference
#define T_   4096
#define E_   8
#define NCON 56    // consumer blocks (total grid = 32 + 32 + 8 + NCON = 128)

typedef unsigned long long ull;

__device__ __forceinline__ float sigm(float x)  { return 1.0f / (1.0f + __expf(-x)); }
__device__ __forceinline__ float tanh_(float x) { return 1.0f - 2.0f / (__expf(2.0f * x) + 1.0f); }

__device__ __forceinline__ ull aload64(const ull* p) {
  return __hip_atomic_load(p, __ATOMIC_RELAXED, __HIP_MEMORY_SCOPE_AGENT);
}
__device__ __forceinline__ int aload32(const int* p) {
  return __hip_atomic_load(p, __ATOMIC_RELAXED, __HIP_MEMORY_SCOPE_AGENT);
}
__device__ __forceinline__ float aloadf(const float* p) {
  return __hip_atomic_load(p, __ATOMIC_RELAXED, __HIP_MEMORY_SCOPE_AGENT);
}
// embed 3-bit generation tag in low mantissa bits (error <= 7 ulp; R3-validated)
__device__ __forceinline__ float tagf(float h, unsigned g) {
  return __uint_as_float((__float_as_uint(h) & ~7u) | g);
}
__device__ __forceinline__ bool tagok4(const ull* v, unsigned g) {
  bool ok = true;
  #pragma unroll
  for (int i = 0; i < 4; ++i) {
    unsigned lo = (unsigned)v[i], hi = (unsigned)(v[i] >> 32);
    ok &= ((lo & 7u) == g) & ((hi & 7u) == g);
  }
  return ok;
}
// barrier draining LDS (lgkm) but not vector memory
__device__ __forceinline__ void lbar() {
  asm volatile("s_waitcnt lgkmcnt(0)\n\ts_barrier" ::: "memory");
}

#define FMA_8(ACC, W, VA, VB)                                   \
  ACC[0] = fmaf((W), (VA).x, ACC[0]); ACC[1] = fmaf((W), (VA).y, ACC[1]); \
  ACC[2] = fmaf((W), (VA).z, ACC[2]); ACC[3] = fmaf((W), (VA).w, ACC[3]); \
  ACC[4] = fmaf((W), (VB).x, ACC[4]); ACC[5] = fmaf((W), (VB).y, ACC[5]); \
  ACC[6] = fmaf((W), (VB).z, ACC[6]); ACC[7] = fmaf((W), (VB).w, ACC[7]);

// ---------------------------------------------------------------------------
// initK: K-major packed weight copies + zero rings / flags.
// ---------------------------------------------------------------------------
__global__ void initK(const float* __restrict__ Wih_p0, const float* __restrict__ Whh_p0,
                      const float* __restrict__ Wih_p1, const float* __restrict__ Whh_p1,
                      const float* __restrict__ Wih_c0, const float* __restrict__ Whh_c0,
                      const float* __restrict__ Wih_c1, const float* __restrict__ Whh_c1,
                      const float* __restrict__ Wih_o,
                      float* wt_p0, float* wt_p1, float* wt_c0, float* wt_c1,
                      float* wt_o1, float* wt_o2, int* zbase) {
  const int NW = 458752 + 524288 + 131072 + 131072 + 131072 + 98304;
  // zero: h0ring 65536 + h1ring 16384 + flagsBC 65536 + flagC 16384
  const int NZ = 65536 + 16384 + 65536 + 16384;
  const int NTOT = NW + NZ;
  const int gsz = gridDim.x * blockDim.x;
  for (int i = blockIdx.x * blockDim.x + threadIdx.x; i < NTOT; i += gsz) {
    int idx = i;
    if (idx < 458752) { int k = idx >> 10, c = idx & 1023;
      int wg = c >> 5, r5 = c & 31, gate = r5 >> 3, jl = r5 & 7;
      int col = gate * 256 + wg * 8 + jl;
      wt_p0[idx] = (k < 192) ? Wih_p0[col * 192 + k] : Whh_p0[col * 256 + (k - 192)]; continue; }
    idx -= 458752;
    if (idx < 524288) { int k = idx >> 10, c = idx & 1023;
      int wg = c >> 5, r5 = c & 31, gate = r5 >> 3, jl = r5 & 7;
      int col = gate * 256 + wg * 8 + jl;
      wt_p1[idx] = (k < 256) ? Wih_p1[col * 256 + k] : Whh_p1[col * 256 + (k - 256)]; continue; }
    idx -= 524288;
    if (idx < 131072) { int k = idx >> 9, r = idx & 511;
      wt_c0[idx] = (k < 128) ? Wih_c0[r * 128 + k] : Whh_c0[r * 128 + (k - 128)]; continue; }
    idx -= 131072;
    if (idx < 131072) { int k = idx >> 9, r = idx & 511;
      wt_c1[idx] = (k < 128) ? Wih_c1[r * 128 + k] : Whh_c1[r * 128 + (k - 128)]; continue; }
    idx -= 131072;
    if (idx < 131072) { int k = idx >> 9, r = idx & 511;
      wt_o1[idx] = Wih_o[r * 448 + k]; continue; }
    idx -= 131072;
    if (idx < 98304) { int k = idx >> 9, r = idx & 511;
      wt_o2[idx] = Wih_o[r * 448 + 256 + k]; continue; }
    idx -= 98304;
    zbase[idx] = 0;
  }
}

// ---------------------------------------------------------------------------
// opre2K: parallel over t. opre2[t][e][512] = Wih_o[:,256:448] @ x(t,e)  (bf16)
// ---------------------------------------------------------------------------
__global__ void opre2K(const float* __restrict__ feat, const float* __restrict__ wt_o2,
                       __hip_bfloat16* __restrict__ opre2) {
  __shared__ float xb[192 * 8];
  const int t = blockIdx.x, tid = threadIdx.x;
  const float* ft = feat + (size_t)t * 640;
  for (int idx = tid; idx < 192 * 8; idx += 256) {
    int k = idx >> 3, e = idx & 7;
    xb[idx] = (k < 128) ? ft[k] : ft[128 + e * 64 + (k - 128)];
  }
  __syncthreads();
  const int r = tid;
  float A0[8] = {0,0,0,0,0,0,0,0};
  float A1[8] = {0,0,0,0,0,0,0,0};
  const float4* x4 = (const float4*)xb;
  #pragma unroll 2
  for (int k = 0; k < 192; ++k) {
    float w0 = wt_o2[k * 512 + r];
    float w1 = wt_o2[k * 512 + 256 + r];
    float4 a = x4[k * 2], b = x4[k * 2 + 1];
    FMA_8(A0, w0, a, b);
    FMA_8(A1, w1, a, b);
  }
  #pragma unroll
  for (int e = 0; e < 8; ++e) {
    opre2[((size_t)t * 8 + e) * 512 + r]       = __float2bfloat16(A0[e]);
    opre2[((size_t)t * 8 + e) * 512 + 256 + r] = __float2bfloat16(A1[e]);
  }
}

// ---------------------------------------------------------------------------
// comm cell (unchanged math)
// ---------------------------------------------------------------------------
__device__ __forceinline__ void comm_cell(
    const float* __restrict__ wt, const float* __restrict__ bias,
    const float* xin, float* hL, float* cL, float* glb, float* hout,
    float alpha, int tid) {
  const int r = tid;
  float A0[8] = {0,0,0,0,0,0,0,0};
  float A1[8] = {0,0,0,0,0,0,0,0};
  const float4* x4 = (const float4*)xin;
  #pragma unroll 2
  for (int k = 0; k < 128; ++k) {
    float w0 = wt[k * 512 + r];
    float w1 = wt[k * 512 + 256 + r];
    float4 a = x4[k * 2], b = x4[k * 2 + 1];
    FMA_8(A0, w0, a, b);
    FMA_8(A1, w1, a, b);
  }
  const float4* h4 = (const float4*)hL;
  #pragma unroll 2
  for (int k = 0; k < 128; ++k) {
    float w0 = wt[(128 + k) * 512 + r];
    float w1 = wt[(128 + k) * 512 + 256 + r];
    float4 a = h4[k * 2], b = h4[k * 2 + 1];
    FMA_8(A0, w0, a, b);
    FMA_8(A1, w1, a, b);
  }
  {
    float4* g4 = (float4*)glb;
    g4[r * 2]             = make_float4(A0[0], A0[1], A0[2], A0[3]);
    g4[r * 2 + 1]         = make_float4(A0[4], A0[5], A0[6], A0[7]);
    g4[(256 + r) * 2]     = make_float4(A1[0], A1[1], A1[2], A1[3]);
    g4[(256 + r) * 2 + 1] = make_float4(A1[4], A1[5], A1[6], A1[7]);
  }
  __syncthreads();
  for (int idx = tid; idx < 1024; idx += 256) {
    int jj = idx >> 3, tt = idx & 7;
    float gi = glb[jj * 8 + tt]         + bias[jj];
    float gf = glb[(128 + jj) * 8 + tt] + bias[128 + jj];
    float gg = glb[(256 + jj) * 8 + tt] + bias[256 + jj];
    float go = glb[(384 + jj) * 8 + tt] + bias[384 + jj];
    float cold = cL[idx], hold = hL[idx];
    float c2 = sigm(gf) * cold + sigm(gi) * tanh_(gg);
    float h2 = sigm(go) * tanh_(c2);
    float hb = fmaf(alpha, h2 - hold, hold);
    float cb = fmaf(alpha, c2 - cold, cold);
    hL[idx] = hb; cL[idx] = cb;
    if (hout) hout[idx] = hb;
  }
  __syncthreads();
}

// ---------------------------------------------------------------------------
// MEGA kernel: 128 blocks, 256 thr, 155648 B LDS => 1 block/CU.
// NEW exchange protocol: the data IS the flag. Producers store h values with
// a 3-bit generation tag in the low mantissa bits (no per-step flag, no
// store ack). Each consuming thread needs exactly 32 B from exactly one
// source block; it issues the 8-value load right after S1, runs the x-matvec
// (~700 cy) while the data is in flight, then verifies the 16 tags and
// retries its own 32 B only if stale. 2 barriers per step (was 4).
//   blocks 0-31  : G1 layer0; h0ring depth 32, free-runs (lag-24 backpressure
//                  on 8-step flagsBC, sleep 16); x double-buffered pre-S1
//   blocks 32-63 : G2 layer1; h1ring depth 8; h0(t+2) prefetched per-thread
//   blocks 64-71 : phaseC per-e output LSTM
//   blocks 72-   : consumers: fused fc+comm per 8-t chunk (flagsBC, sleep 64)
// flagsBC (G2 -> consumers + G1 backpressure) is the only remaining flag:
// published once per 8 steps with a wave-local vmcnt(0) ack (orders h1all).
// Gen-tag windows: h0 gen=(t>>5)%7+1 (ring 32, alias at lag 224 >> bp 32);
// h1 gen=(t>>3)%7+1 (ring 8, lockstep lag 1). Rings zero-initialized (tag 0
// never matches gens 1..7).
// ---------------------------------------------------------------------------
__launch_bounds__(256, 1)
__global__ void megaK(const float* __restrict__ feat,
                      const float* __restrict__ pre_h0, const float* __restrict__ pre_c0,
                      const float* __restrict__ wt_p0, const float* __restrict__ wt_p1,
                      const float* __restrict__ b_p0, const float* __restrict__ b_p1,
                      float* __restrict__ h0ring, float* __restrict__ h1ring,
                      float* __restrict__ h1all, int* __restrict__ flagsBC,
                      const float* __restrict__ Wfc, const float* __restrict__ bfc,
                      const float* __restrict__ wt_c0, const float* __restrict__ wt_c1,
                      const float* __restrict__ b_c0, const float* __restrict__ b_c1,
                      const float* __restrict__ wt_o1, const float* __restrict__ b_o,
                      float* __restrict__ opre1, int* __restrict__ flagC,
                      const __hip_bfloat16* __restrict__ opre2,
                      const float* __restrict__ Whh_o, const float* __restrict__ out_h0,
                      const float* __restrict__ out_c0, float* __restrict__ oh_g) {
  __shared__ float lds[38912];   // 155,648 B
  const int wg = blockIdx.x, tid = threadIdx.x;

  if (wg < 32) {
    // ============================ G1: layer0 (32 blocks) ============================
    float* wl  = lds;             // 14336: weights [k][32], k<448
    float* xb0 = lds + 14336;     // 1536 (x double buffer A)
    float* xb1 = lds + 15872;     // 1536 (x double buffer B)
    float* hsf = lds + 17408;     // 2048
    float* gl  = lds + 19456;     // 2048 partials
    const int r5 = tid & 31, kq = tid >> 5;
    for (int idx = tid; idx < 14336; idx += 256)
      wl[idx] = wt_p0[(size_t)(idx >> 5) * 1024 + wg * 32 + (idx & 31)];
    float creg = 0.f, bi = 0.f, bff = 0.f, bg = 0.f, bo = 0.f;
    if (tid < 64) {
      const int jl = tid >> 3, e = tid & 7, j = wg * 8 + jl;
      creg = pre_c0[(e * 2 + 0) * 256 + j];
      bi = b_p0[j]; bff = b_p0[256 + j]; bg = b_p0[512 + j]; bo = b_p0[768 + j];
    }
    for (int idx = tid; idx < 2048; idx += 256) {
      int k = idx >> 3, e = idx & 7;
      hsf[idx] = pre_h0[(e * 2 + 0) * 256 + k];
    }
    for (int idx = tid; idx < 1536; idx += 256) {
      int k = idx >> 3, e = idx & 7;
      xb0[idx] = (k < 128) ? feat[k] : feat[128 + e * 64 + (k - 128)];
    }
    __syncthreads();
    const bool own = ((tid >> 3) == wg);
    float Ax[8] = {0,0,0,0,0,0,0,0};
    {
      const float4* x4 = (const float4*)xb0;
      #pragma unroll
      for (int k = kq * 24; k < kq * 24 + 24; ++k) {
        float w = wl[k * 32 + r5];
        float4 a = x4[k * 2], b = x4[k * 2 + 1];
        FMA_8(Ax, w, a, b);
      }
    }
    for (int t = 0; t < T_; ++t) {
      float px[6];
      if (t + 1 < T_) {
        const float* ft1 = feat + (size_t)(t + 1) * 640;
        #pragma unroll
        for (int i = 0; i < 6; ++i) {
          int idx = tid + i * 256; int k = idx >> 3, e = idx & 7;
          px[i] = (k < 128) ? ft1[k] : ft1[128 + e * 64 + (k - 128)];
        }
      }
      float A[8];
      #pragma unroll
      for (int i = 0; i < 8; ++i) A[i] = Ax[i];
      {
        const float4* h4 = (const float4*)hsf;
        #pragma unroll
        for (int k2 = 0; k2 < 32; ++k2) {
          const int k = kq * 32 + k2;
          float w = wl[(192 + k) * 32 + r5];
          float4 a = h4[k * 2], b = h4[k * 2 + 1];
          FMA_8(A, w, a, b);
        }
      }
      {
        float4* g4 = (float4*)gl;
        g4[(kq * 32 + r5) * 2]     = make_float4(A[0], A[1], A[2], A[3]);
        g4[(kq * 32 + r5) * 2 + 1] = make_float4(A[4], A[5], A[6], A[7]);
      }
      if (t + 1 < T_) {                            // stage x(t+1) into alt buffer
        float* xbN = ((t + 1) & 1) ? xb1 : xb0;
        #pragma unroll
        for (int i = 0; i < 6; ++i) xbN[tid + i * 256] = px[i];
      }
      if (t >= 24 && tid >= 224) {                 // back-pressure, lag 24 (8-step gran)
        const int t2 = (t - 24) | 7;
        const int* fp = flagsBC + ((size_t)(t2 & 63) * 32 + (tid - 224)) * 32;
        while (aload32(fp) < t2 + 1) __builtin_amdgcn_s_sleep(16);
      }
      lbar();                                      // S1
      const unsigned g = ((unsigned)(t >> 5) % 7u) + 1u;
      float* ringS = h0ring + (size_t)(t & 31) * 2048;
      if (tid < 64) {
        float s0 = 0.f, s1 = 0.f, s2 = 0.f, s3 = 0.f;
        #pragma unroll
        for (int q = 0; q < 8; ++q) {
          s0 += gl[q * 256 + tid];       s1 += gl[q * 256 + 64 + tid];
          s2 += gl[q * 256 + 128 + tid]; s3 += gl[q * 256 + 192 + tid];
        }
        float c2 = sigm(s1 + bff) * creg + sigm(s0 + bi) * tanh_(s2 + bg);
        float h2 = sigm(s3 + bo) * tanh_(c2);
        creg = c2;
        __hip_atomic_store(&ringS[wg * 64 + tid], tagf(h2, g),
                           __ATOMIC_RELAXED, __HIP_MEMORY_SCOPE_AGENT);
        hsf[wg * 64 + tid] = h2;                   // own slice direct to LDS
      }
      if (t + 1 >= T_) break;
      ull v[4];
      const ull* rp = (const ull*)ringS + tid * 4;
      if (!own) {
        #pragma unroll
        for (int i = 0; i < 4; ++i) v[i] = aload64(rp + i);  // in flight
      }
      #pragma unroll
      for (int i = 0; i < 8; ++i) Ax[i] = 0.f;
      {                                            // x-matvec hides data flight
        const float4* x4 = (const float4*)(((t + 1) & 1) ? xb1 : xb0);
        #pragma unroll
        for (int k = kq * 24; k < kq * 24 + 24; ++k) {
          float w = wl[k * 32 + r5];
          float4 a = x4[k * 2], b = x4[k * 2 + 1];
          FMA_8(Ax, w, a, b);
        }
      }
      if (!own) {
        while (!tagok4(v, g)) {                    // retry own 32 B only
          __builtin_amdgcn_s_sleep(1);
          #pragma unroll
          for (int i = 0; i < 4; ++i) v[i] = aload64(rp + i);
        }
        ull* d8 = (ull*)hsf;
        #pragma unroll
        for (int i = 0; i < 4; ++i) d8[tid * 4 + i] = v[i];
      }
      lbar();                                      // S4
    }
  } else if (wg < 64) {
    // ============================ G2: layer1 (32 blocks) ============================
    const int wgl = wg - 32;
    float* wl  = lds;             // 16384: weights [k][32], k<512
    float* xh0 = lds + 16384;     // 2048
    float* hsf = lds + 18432;     // 2048
    float* gl  = lds + 20480;     // 2048
    const int r5 = tid & 31, kq = tid >> 5;
    for (int idx = tid; idx < 16384; idx += 256)
      wl[idx] = wt_p1[(size_t)(idx >> 5) * 1024 + wgl * 32 + (idx & 31)];
    float creg = 0.f, bi = 0.f, bff = 0.f, bg = 0.f, bo = 0.f;
    if (tid < 64) {
      const int jl = tid >> 3, e = tid & 7, j = wgl * 8 + jl;
      creg = pre_c0[(e * 2 + 1) * 256 + j];
      bi = b_p1[j]; bff = b_p1[256 + j]; bg = b_p1[512 + j]; bo = b_p1[768 + j];
    }
    for (int idx = tid; idx < 2048; idx += 256) {
      int k = idx >> 3, e = idx & 7;
      hsf[idx] = pre_h0[(e * 2 + 1) * 256 + k];
    }
    __syncthreads();
    const bool own = ((tid >> 3) == wgl);
    ull pv[4];
    {                                              // prologue: h0(0) -> xh0 (gen 1)
      ull v[4];
      const ull* rp = (const ull*)h0ring + tid * 4;
      #pragma unroll
      for (int i = 0; i < 4; ++i) v[i] = aload64(rp + i);
      while (!tagok4(v, 1u)) {
        __builtin_amdgcn_s_sleep(1);
        #pragma unroll
        for (int i = 0; i < 4; ++i) v[i] = aload64(rp + i);
      }
      ull* d8 = (ull*)xh0;
      #pragma unroll
      for (int i = 0; i < 4; ++i) d8[tid * 4 + i] = v[i];
    }
    lbar();
    float Ax[8] = {0,0,0,0,0,0,0,0};
    {
      const float4* x4 = (const float4*)xh0;
      #pragma unroll
      for (int k = kq * 32; k < kq * 32 + 32; ++k) {
        float w = wl[k * 32 + r5];
        float4 a = x4[k * 2], b = x4[k * 2 + 1];
        FMA_8(Ax, w, a, b);
      }
    }
    {                                              // prologue: h0(1) -> pv (gen 1)
      const ull* rp = (const ull*)(h0ring + 2048) + tid * 4;
      #pragma unroll
      for (int i = 0; i < 4; ++i) pv[i] = aload64(rp + i);
      while (!tagok4(pv, 1u)) {
        __builtin_amdgcn_s_sleep(1);
        #pragma unroll
        for (int i = 0; i < 4; ++i) pv[i] = aload64(rp + i);
      }
    }
    lbar();                                        // xh0 reads done before t=0 stage
    for (int t = 0; t < T_; ++t) {
      float A[8];
      #pragma unroll
      for (int i = 0; i < 8; ++i) A[i] = Ax[i];
      {
        const float4* h4 = (const float4*)hsf;
        #pragma unroll
        for (int k2 = 0; k2 < 32; ++k2) {
          const int k = kq * 32 + k2;
          float w = wl[(256 + k) * 32 + r5];
          float4 a = h4[k * 2], b = h4[k * 2 + 1];
          FMA_8(A, w, a, b);
        }
      }
      {
        float4* g4 = (float4*)gl;
        g4[(kq * 32 + r5) * 2]     = make_float4(A[0], A[1], A[2], A[3]);
        g4[(kq * 32 + r5) * 2 + 1] = make_float4(A[4], A[5], A[6], A[7]);
      }
      if (t + 1 < T_) {                            // stage xh0 = h0(t+1) from pv
        ull* d8 = (ull*)xh0;
        #pragma unroll
        for (int i = 0; i < 4; ++i) d8[tid * 4 + i] = pv[i];
      }
      lbar();                                      // S1
      const unsigned g1 = ((unsigned)(t >> 3) % 7u) + 1u;
      float* ringS = h1ring + (size_t)(t & 7) * 2048;
      if (tid < 64) {
        float s0 = 0.f, s1 = 0.f, s2 = 0.f, s3 = 0.f;
        #pragma unroll
        for (int q = 0; q < 8; ++q) {
          s0 += gl[q * 256 + tid];       s1 += gl[q * 256 + 64 + tid];
          s2 += gl[q * 256 + 128 + tid]; s3 += gl[q * 256 + 192 + tid];
        }
        float c2 = sigm(s1 + bff) * creg + sigm(s0 + bi) * tanh_(s2 + bg);
        float h2 = sigm(s3 + bo) * tanh_(c2);
        creg = c2;
        __hip_atomic_store(&ringS[wgl * 64 + tid], tagf(h2, g1),
                           __ATOMIC_RELAXED, __HIP_MEMORY_SCOPE_AGENT);
        hsf[wgl * 64 + tid] = h2;                  // own slice direct to LDS
        __hip_atomic_store(&h1all[(size_t)t * 2048 + wgl * 64 + tid], h2,
                           __ATOMIC_RELAXED, __HIP_MEMORY_SCOPE_AGENT);
        if ((t & 7) == 7) {                        // acked consumer-facing flag
          asm volatile("s_waitcnt vmcnt(0)" ::: "memory");  // drains h1all
          if (tid == 0)
            __hip_atomic_store(&flagsBC[((size_t)(t & 63) * 32 + wgl) * 32], t + 1,
                               __ATOMIC_RELAXED, __HIP_MEMORY_SCOPE_AGENT);
        }
      }
      if (t + 1 >= T_) break;
      ull w1[4];
      const ull* rp1 = (const ull*)ringS + tid * 4;
      if (!own) {
        #pragma unroll
        for (int i = 0; i < 4; ++i) w1[i] = aload64(rp1 + i);  // in flight
      }
      #pragma unroll
      for (int i = 0; i < 8; ++i) Ax[i] = 0.f;
      {                                            // x-matvec hides data flight
        const float4* x4 = (const float4*)xh0;
        #pragma unroll
        for (int k = kq * 32; k < kq * 32 + 32; ++k) {
          float w = wl[k * 32 + r5];
          float4 a = x4[k * 2], b = x4[k * 2 + 1];
          FMA_8(Ax, w, a, b);
        }
      }
      if (!own) {
        while (!tagok4(w1, g1)) {
          __builtin_amdgcn_s_sleep(1);
          #pragma unroll
          for (int i = 0; i < 4; ++i) w1[i] = aload64(rp1 + i);
        }
        ull* d8 = (ull*)hsf;
        #pragma unroll
        for (int i = 0; i < 4; ++i) d8[tid * 4 + i] = w1[i];
      }
      if (t + 2 < T_) {                            // prefetch h0(t+2): G1 is far
        const unsigned g0 = ((unsigned)((t + 2) >> 5) % 7u) + 1u;
        const ull* rp0 = (const ull*)(h0ring + (size_t)((t + 2) & 31) * 2048) + tid * 4;
        #pragma unroll
        for (int i = 0; i < 4; ++i) pv[i] = aload64(rp0 + i);
        while (!tagok4(pv, g0)) {                  // ahead via backpressure: rare spin
          __builtin_amdgcn_s_sleep(1);
          #pragma unroll
          for (int i = 0; i < 4; ++i) pv[i] = aload64(rp0 + i);
        }
      }
      lbar();                                      // S4
    }
  } else if (wg < 72) {
    // ============================ phaseC (per e) ============================
    const int e = wg - 64;
    float* wlds = lds;            // [k][256] rows 256-511: 32768 floats
    float* ohl  = lds + 32768;    // 128
    float* gl   = lds + 32896;    // 512
    for (int idx = tid; idx < 32768; idx += 256) {
      int k = idx >> 8, rr = idx & 255;
      wlds[idx] = Whh_o[(256 + rr) * 128 + k];
    }
    float w[128];
    #pragma unroll
    for (int k = 0; k < 128; ++k) w[k] = Whh_o[tid * 128 + k];
    if (tid < 128) ohl[tid] = out_h0[e * 128 + tid];
    float creg = (tid < 128) ? out_c0[e * 128 + tid] : 0.f;
    __syncthreads();
    if (tid == 0) { while (aload32(&flagC[0]) == 0) __builtin_amdgcn_s_sleep(4); }
    __syncthreads();
    const int r0 = tid, r1 = tid + 256;
    float pa = aloadf(&opre1[r0]), pb = aloadf(&opre1[r1]);
    float qa = __bfloat162float(opre2[(size_t)e * 512 + r0]);
    float qb = __bfloat162float(opre2[(size_t)e * 512 + r1]);
    float na = aloadf(&opre1[512 + r0]), nb = aloadf(&opre1[512 + r1]);
    float ma = __bfloat162float(opre2[(size_t)(8 + e) * 512 + r0]);
    float mb = __bfloat162float(opre2[(size_t)(8 + e) * 512 + r1]);
    for (int t = 0; t < T_; ++t) {
      float a0 = pa + qa, a1 = pb + qb;
      pa = na; pb = nb; qa = ma; qb = mb;
      if ((t & 7) == 6 && t + 2 < T_) {            // next chunk ready?
        if (tid == 0) { while (aload32(&flagC[((t + 2) >> 3) * 32]) == 0) __builtin_amdgcn_s_sleep(4); }
        __syncthreads();
      }
      if (t + 2 < T_) {
        na = aloadf(&opre1[(size_t)(t + 2) * 512 + r0]);
        nb = aloadf(&opre1[(size_t)(t + 2) * 512 + r1]);
        ma = __bfloat162float(opre2[((size_t)(t + 2) * 8 + e) * 512 + r0]);
        mb = __bfloat162float(opre2[((size_t)(t + 2) * 8 + e) * 512 + r1]);
      }
      const float4* o4 = (const float4*)ohl;
      #pragma unroll
      for (int kk = 0; kk < 32; ++kk) {
        float4 x = o4[kk];
        a0 = fmaf(w[kk * 4 + 0], x.x, a0); a0 = fmaf(w[kk * 4 + 1], x.y, a0);
        a0 = fmaf(w[kk * 4 + 2], x.z, a0); a0 = fmaf(w[kk * 4 + 3], x.w, a0);
        a1 = fmaf(wlds[(kk * 4 + 0) * 256 + tid], x.x, a1);
        a1 = fmaf(wlds[(kk * 4 + 1) * 256 + tid], x.y, a1);
        a1 = fmaf(wlds[(kk * 4 + 2) * 256 + tid], x.z, a1);
        a1 = fmaf(wlds[(kk * 4 + 3) * 256 + tid], x.w, a1);
      }
      gl[r0] = a0; gl[r1] = a1;
      __syncthreads();
      if (tid < 128) {
        float gi = gl[tid], gf = gl[128 + tid], gg = gl[256 + tid], go = gl[384 + tid];
        float c2 = sigm(gf) * creg + sigm(gi) * tanh_(gg);
        float h2 = sigm(go) * tanh_(c2);
        creg = c2;
        ohl[tid] = h2;
        oh_g[(size_t)t * 1024 + e * 128 + tid] = h2;
      }
      __syncthreads();
    }
  } else {
    // ==================== consumers: fused fc + comm ====================
    const int cb = wg - 72;
    float* h1c    = lds;          // 16384
    float* polAll = lds + 16384;  // 8192
    float* ch0 = lds + 24576; float* cc0 = lds + 25600;
    float* ch1 = lds + 26624; float* cc1 = lds + 27648;
    float* h0b = lds + 28672;     // 1024
    float* glb = lds + 29696;     // 4096
    for (int chunk = cb; chunk < 512; chunk += NCON) {
      const int t0 = chunk * 8;
      if (tid < 32) {
        const int* fp = flagsBC + ((size_t)((t0 + 7) & 63) * 32 + tid) * 32;
        while (aload32(fp) < t0 + 8) __builtin_amdgcn_s_sleep(64);
      }
      __syncthreads();
      {
        const ull* src = (const ull*)(h1all + (size_t)t0 * 2048);
        ull* dst = (ull*)h1c;
        for (int i = tid; i < 8192; i += 256) dst[i] = aload64(src + i);
      }
      __syncthreads();
      {  // fc for 8 ts -> polAll[e][c*8+tt]
        const int c = tid >> 1, half = tid & 1;
        const float bv = bfc[c];
        const float* wrow = Wfc + c * 256;
        for (int tt = 0; tt < 8; ++tt) {
          float a0 = bv, a1 = bv, a2 = bv, a3 = bv;
          const float4* h4 = (const float4*)(h1c + tt * 2048);
          #pragma unroll 4
          for (int k = 0; k < 256; ++k) {
            float wv = wrow[k];
            float4 x = h4[k * 2 + half];
            a0 = fmaf(wv, x.x, a0); a1 = fmaf(wv, x.y, a1);
            a2 = fmaf(wv, x.z, a2); a3 = fmaf(wv, x.w, a3);
          }
          float vv[4] = {a0, a1, a2, a3};
          #pragma unroll
          for (int i = 0; i < 4; ++i) {
            float v = vv[i];
            v = (v > 0.f) ? v : 0.05f * v;
            polAll[(half * 4 + i) * 1024 + c * 8 + tt] = v;
          }
        }
      }
      for (int idx = tid; idx < 1024; idx += 256) { ch0[idx]=0.f; cc0[idx]=0.f; ch1[idx]=0.f; cc1[idx]=0.f; }
      __syncthreads();
      float alpha = 1.0f;
      for (int rd = 0; rd < 3; ++rd) {
        for (int e = 0; e < E_; ++e) {
          comm_cell(wt_c0, b_c0, polAll + e * 1024, ch0, cc0, glb, h0b, alpha, tid);
          comm_cell(wt_c1, b_c1, h0b, ch1, cc1, glb, nullptr, alpha, tid);
        }
        alpha *= 0.333f;
      }
      {  // opre1 epilogue (atomic stores for intra-kernel visibility)
        const int r = tid;
        float A0[8], A1[8];
        #pragma unroll
        for (int tt = 0; tt < 8; ++tt) { A0[tt] = b_o[r]; A1[tt] = b_o[256 + r]; }
        const float4* c04 = (const float4*)cc0;
        const float4* c14 = (const float4*)cc1;
        #pragma unroll 2
        for (int k = 0; k < 128; ++k) {
          float w0 = wt_o1[k * 512 + r], w1 = wt_o1[k * 512 + 256 + r];
          float4 a = c04[k * 2], b = c04[k * 2 + 1];
          FMA_8(A0, w0, a, b);
          FMA_8(A1, w1, a, b);
        }
        #pragma unroll 2
        for (int k = 0; k < 128; ++k) {
          float w0 = wt_o1[(128 + k) * 512 + r], w1 = wt_o1[(128 + k) * 512 + 256 + r];
          float4 a = c14[k * 2], b = c14[k * 2 + 1];
          FMA_8(A0, w0, a, b);
          FMA_8(A1, w1, a, b);
        }
        #pragma unroll
        for (int tt = 0; tt < 8; ++tt) {
          __hip_atomic_store(&opre1[((size_t)(t0 + tt)) * 512 + r], A0[tt],
                             __ATOMIC_RELAXED, __HIP_MEMORY_SCOPE_AGENT);
          __hip_atomic_store(&opre1[((size_t)(t0 + tt)) * 512 + 256 + r], A1[tt],
                             __ATOMIC_RELAXED, __HIP_MEMORY_SCOPE_AGENT);
        }
      }
      __syncthreads();                             // drain opre1 (vmcnt0)
      if (tid == 0)
        __hip_atomic_store(&flagC[chunk * 32], 1, __ATOMIC_RELAXED, __HIP_MEMORY_SCOPE_AGENT);
      __syncthreads();
    }
  }
}

// ---------------------------------------------------------------------------
// phaseD: parallel over t: softmaxes
// ---------------------------------------------------------------------------
__global__ void phaseD(const float* __restrict__ oh_g,
                       const float* __restrict__ Wtar, const float* __restrict__ btar,
                       const float* __restrict__ Wdir, const float* __restrict__ bdir,
                       float* __restrict__ outp) {
  __shared__ float ohl[1024];
  const int t = blockIdx.x, tid = threadIdx.x;  // 64 threads
  for (int idx = tid; idx < 1024; idx += 64) ohl[idx] = oh_g[(size_t)t * 1024 + idx];
  __syncthreads();
  const int f = tid;
  for (int e = 0; e < E_; ++e) {
    float acc = btar[f];
    const float* wr = Wtar + f * 128;
    #pragma unroll 4
    for (int k = 0; k < 128; ++k) acc = fmaf(wr[k], ohl[e * 128 + k], acc);
    float m = acc;
    #pragma unroll
    for (int off = 32; off; off >>= 1) m = fmaxf(m, __shfl_xor(m, off, 64));
    float ex = __expf(acc - m);
    float s = ex;
    #pragma unroll
    for (int off = 32; off; off >>= 1) s += __shfl_xor(s, off, 64);
    outp[((size_t)t * 8 + e) * 64 + f] = ex / s;
  }
  if (tid < 8) {
    int e = tid;
    float d0 = bdir[0], d1 = bdir[1], d2 = bdir[2];
    #pragma unroll 4
    for (int k = 0; k < 128; ++k) {
      float x = ohl[e * 128 + k];
      d0 = fmaf(Wdir[k], x, d0);
      d1 = fmaf(Wdir[128 + k], x, d1);
      d2 = fmaf(Wdir[256 + k], x, d2);
    }
    float m = fmaxf(d0, fmaxf(d1, d2));
    float x0 = __expf(d0 - m), x1 = __expf(d1 - m), x2 = __expf(d2 - m);
    float s = x0 + x1 + x2;
    float* dp = outp + (size_t)T_ * 8 * 64 + ((size_t)t * 8 + e) * 3;
    dp[0] = x0 / s; dp[1] = x1 / s; dp[2] = x2 / s;
  }
}

extern "C" void kernel_launch(void* const* d_in, const int* in_sizes, int n_in,
                              void* d_out, int out_size, void* d_ws, size_t ws_size,
                              hipStream_t stream) {
  (void)in_sizes; (void)n_in; (void)out_size; (void)ws_size;
  const float* feat   = (const float*)d_in[0];
  const float* pre_h0 = (const float*)d_in[1];
  const float* pre_c0 = (const float*)d_in[2];
  const float* out_h0 = (const float*)d_in[3];
  const float* out_c0 = (const float*)d_in[4];
  const float* Wih_p0 = (const float*)d_in[5];
  const float* Whh_p0 = (const float*)d_in[6];
  const float* b_p0   = (const float*)d_in[7];
  const float* Wih_p1 = (const float*)d_in[8];
  const float* Whh_p1 = (const float*)d_in[9];
  const float* b_p1   = (const float*)d_in[10];
  const float* Wfc    = (const float*)d_in[11];
  const float* bfc    = (const float*)d_in[12];
  const float* Wih_c0 = (const float*)d_in[13];
  const float* Whh_c0 = (const float*)d_in[14];
  const float* b_c0   = (const float*)d_in[15];
  const float* Wih_c1 = (const float*)d_in[16];
  const float* Whh_c1 = (const float*)d_in[17];
  const float* b_c1   = (const float*)d_in[18];
  const float* Wih_o  = (const float*)d_in[19];
  const float* Whh_o  = (const float*)d_in[20];
  const float* b_o    = (const float*)d_in[21];
  const float* Wtar   = (const float*)d_in[22];
  const float* btar   = (const float*)d_in[23];
  const float* Wdir   = (const float*)d_in[24];
  const float* bdir   = (const float*)d_in[25];
  float* outp = (float*)d_out;

  float* ws = (float*)d_ws;
  size_t off = 0;
  float* opre1    = ws + off; off += (size_t)T_ * 512;
  float* oh_g     = ws + off; off += (size_t)T_ * E_ * 128;
  float* wt_p0    = ws + off; off += (size_t)448 * 1024;
  float* wt_p1    = ws + off; off += (size_t)512 * 1024;
  float* wt_c0    = ws + off; off += (size_t)256 * 512;
  float* wt_c1    = ws + off; off += (size_t)256 * 512;
  float* wt_o1    = ws + off; off += (size_t)256 * 512;
  float* wt_o2    = ws + off; off += (size_t)192 * 512;
  __hip_bfloat16* opre2 = (__hip_bfloat16*)(ws + off);
  off += (size_t)T_ * E_ * 512 / 2;
  float* h1all  = ws + off; off += (size_t)T_ * 2048;
  float* h0ring = ws + off; off += (size_t)32 * 2048;   // tagged, depth 32
  float* h1ring = ws + off; off += (size_t)8 * 2048;    // tagged, depth 8
  int* flags    = (int*)(ws + off);
  int* flagsBC  = flags;                                 // 64*32*32 (8-step, acked)
  int* flagC    = flags + (size_t)64 * 32 * 32;          // 512*32
  int* zbase    = (int*)h0ring;   // zero span: rings + flags

  initK<<<dim3(1024), dim3(256), 0, stream>>>(
      Wih_p0, Whh_p0, Wih_p1, Whh_p1, Wih_c0, Whh_c0, Wih_c1, Whh_c1, Wih_o,
      wt_p0, wt_p1, wt_c0, wt_c1, wt_o1, wt_o2, zbase);
  opre2K<<<dim3(T_), dim3(256), 0, stream>>>(feat, wt_o2, opre2);
  megaK<<<dim3(32 + 32 + 8 + NCON), dim3(256), 0, stream>>>(
      feat, pre_h0, pre_c0, wt_p0, wt_p1, b_p0, b_p1,
      h0ring, h1ring, h1all, flagsBC,
      Wfc, bfc, wt_c0, wt_c1, b_c0, b_c1, wt_o1, b_o, opre1, flagC,
      opre2, Whh_o, out_h0, out_c0, oh_g);
  phaseD<<<dim3(T_), dim3(64), 0, stream>>>(oh_g, Wtar, btar, Wdir, bdir, outp);
}

// Round 8
// 15561.113 us; speedup vs baseline: 1.6229x; 1.0144x over previous
//
#include <hip/hip_runtime.h>
#include <hip/hip_bf16.h>

// Sizes from the reference
#define T_   4096
#define E_   8
#define NCON 56    // consumer blocks

typedef unsigned long long ull;

__device__ __forceinline__ float sigm(float x)  { return 1.0f / (1.0f + __expf(-x)); }
__device__ __forceinline__ float tanh_(float x) { return 1.0f - 2.0f / (__expf(2.0f * x) + 1.0f); }

__device__ __forceinline__ ull aload64(const ull* p) {
  return __hip_atomic_load(p, __ATOMIC_RELAXED, __HIP_MEMORY_SCOPE_AGENT);
}
__device__ __forceinline__ int aload32(const int* p) {
  return __hip_atomic_load(p, __ATOMIC_RELAXED, __HIP_MEMORY_SCOPE_AGENT);
}
__device__ __forceinline__ float aloadf(const float* p) {
  return __hip_atomic_load(p, __ATOMIC_RELAXED, __HIP_MEMORY_SCOPE_AGENT);
}
// embed 3-bit generation tag in low mantissa bits (error <= 7 ulp; R3-validated)
__device__ __forceinline__ float tagf(float h, unsigned g) {
  return __uint_as_float((__float_as_uint(h) & ~7u) | g);
}
__device__ __forceinline__ bool tagok4(const ull* v, unsigned g) {
  bool ok = true;
  #pragma unroll
  for (int i = 0; i < 4; ++i) {
    unsigned lo = (unsigned)v[i], hi = (unsigned)(v[i] >> 32);
    ok &= ((lo & 7u) == g) & ((hi & 7u) == g);
  }
  return ok;
}
// barrier draining LDS (lgkm) but not vector memory
__device__ __forceinline__ void lbar() {
  asm volatile("s_waitcnt lgkmcnt(0)\n\ts_barrier" ::: "memory");
}

#define FMA_8(ACC, W, VA, VB)                                   \
  ACC[0] = fmaf((W), (VA).x, ACC[0]); ACC[1] = fmaf((W), (VA).y, ACC[1]); \
  ACC[2] = fmaf((W), (VA).z, ACC[2]); ACC[3] = fmaf((W), (VA).w, ACC[3]); \
  ACC[4] = fmaf((W), (VB).x, ACC[4]); ACC[5] = fmaf((W), (VB).y, ACC[5]); \
  ACC[6] = fmaf((W), (VB).z, ACC[6]); ACC[7] = fmaf((W), (VB).w, ACC[7]);

// ---------------------------------------------------------------------------
// initK: K-major packed weight copies + zero rings / flags.
// ---------------------------------------------------------------------------
__global__ void initK(const float* __restrict__ Wih_p0, const float* __restrict__ Whh_p0,
                      const float* __restrict__ Wih_p1, const float* __restrict__ Whh_p1,
                      const float* __restrict__ Wih_c0, const float* __restrict__ Whh_c0,
                      const float* __restrict__ Wih_c1, const float* __restrict__ Whh_c1,
                      const float* __restrict__ Wih_o,
                      float* wt_p0, float* wt_p1, float* wt_c0, float* wt_c1,
                      float* wt_o1, float* wt_o2, int* zbase) {
  const int NW = 458752 + 524288 + 131072 + 131072 + 131072 + 98304;
  // zero: h0ringL 65536 + h0ringG 65536 + h1ringL 16384 + flagsBC 65536 + flagC 16384
  const int NZ = 65536 + 65536 + 16384 + 65536 + 16384;
  const int NTOT = NW + NZ;
  const int gsz = gridDim.x * blockDim.x;
  for (int i = blockIdx.x * blockDim.x + threadIdx.x; i < NTOT; i += gsz) {
    int idx = i;
    if (idx < 458752) { int k = idx >> 10, c = idx & 1023;
      int wg = c >> 5, r5 = c & 31, gate = r5 >> 3, jl = r5 & 7;
      int col = gate * 256 + wg * 8 + jl;
      wt_p0[idx] = (k < 192) ? Wih_p0[col * 192 + k] : Whh_p0[col * 256 + (k - 192)]; continue; }
    idx -= 458752;
    if (idx < 524288) { int k = idx >> 10, c = idx & 1023;
      int wg = c >> 5, r5 = c & 31, gate = r5 >> 3, jl = r5 & 7;
      int col = gate * 256 + wg * 8 + jl;
      wt_p1[idx] = (k < 256) ? Wih_p1[col * 256 + k] : Whh_p1[col * 256 + (k - 256)]; continue; }
    idx -= 524288;
    if (idx < 131072) { int k = idx >> 9, r = idx & 511;
      wt_c0[idx] = (k < 128) ? Wih_c0[r * 128 + k] : Whh_c0[r * 128 + (k - 128)]; continue; }
    idx -= 131072;
    if (idx < 131072) { int k = idx >> 9, r = idx & 511;
      wt_c1[idx] = (k < 128) ? Wih_c1[r * 128 + k] : Whh_c1[r * 128 + (k - 128)]; continue; }
    idx -= 131072;
    if (idx < 131072) { int k = idx >> 9, r = idx & 511;
      wt_o1[idx] = Wih_o[r * 448 + k]; continue; }
    idx -= 131072;
    if (idx < 98304) { int k = idx >> 9, r = idx & 511;
      wt_o2[idx] = Wih_o[r * 448 + 256 + k]; continue; }
    idx -= 98304;
    zbase[idx] = 0;
  }
}

// ---------------------------------------------------------------------------
// opre2K: parallel over t. opre2[t][e][512] = Wih_o[:,256:448] @ x(t,e)  (bf16)
// ---------------------------------------------------------------------------
__global__ void opre2K(const float* __restrict__ feat, const float* __restrict__ wt_o2,
                       __hip_bfloat16* __restrict__ opre2) {
  __shared__ float xb[192 * 8];
  const int t = blockIdx.x, tid = threadIdx.x;
  const float* ft = feat + (size_t)t * 640;
  for (int idx = tid; idx < 192 * 8; idx += 256) {
    int k = idx >> 3, e = idx & 7;
    xb[idx] = (k < 128) ? ft[k] : ft[128 + e * 64 + (k - 128)];
  }
  __syncthreads();
  const int r = tid;
  float A0[8] = {0,0,0,0,0,0,0,0};
  float A1[8] = {0,0,0,0,0,0,0,0};
  const float4* x4 = (const float4*)xb;
  #pragma unroll 2
  for (int k = 0; k < 192; ++k) {
    float w0 = wt_o2[k * 512 + r];
    float w1 = wt_o2[k * 512 + 256 + r];
    float4 a = x4[k * 2], b = x4[k * 2 + 1];
    FMA_8(A0, w0, a, b);
    FMA_8(A1, w1, a, b);
  }
  #pragma unroll
  for (int e = 0; e < 8; ++e) {
    opre2[((size_t)t * 8 + e) * 512 + r]       = __float2bfloat16(A0[e]);
    opre2[((size_t)t * 8 + e) * 512 + 256 + r] = __float2bfloat16(A1[e]);
  }
}

// ---------------------------------------------------------------------------
// comm cell (unchanged math; guarded for 256 active threads)
// ---------------------------------------------------------------------------
__device__ __forceinline__ void comm_cell(
    const float* __restrict__ wt, const float* __restrict__ bias,
    const float* xin, float* hL, float* cL, float* glb, float* hout,
    float alpha, int tid) {
  const int r = tid;
  float A0[8] = {0,0,0,0,0,0,0,0};
  float A1[8] = {0,0,0,0,0,0,0,0};
  const float4* x4 = (const float4*)xin;
  #pragma unroll 2
  for (int k = 0; k < 128; ++k) {
    float w0 = wt[k * 512 + r];
    float w1 = wt[k * 512 + 256 + r];
    float4 a = x4[k * 2], b = x4[k * 2 + 1];
    FMA_8(A0, w0, a, b);
    FMA_8(A1, w1, a, b);
  }
  const float4* h4 = (const float4*)hL;
  #pragma unroll 2
  for (int k = 0; k < 128; ++k) {
    float w0 = wt[(128 + k) * 512 + r];
    float w1 = wt[(128 + k) * 512 + 256 + r];
    float4 a = h4[k * 2], b = h4[k * 2 + 1];
    FMA_8(A0, w0, a, b);
    FMA_8(A1, w1, a, b);
  }
  {
    float4* g4 = (float4*)glb;
    g4[r * 2]             = make_float4(A0[0], A0[1], A0[2], A0[3]);
    g4[r * 2 + 1]         = make_float4(A0[4], A0[5], A0[6], A0[7]);
    g4[(256 + r) * 2]     = make_float4(A1[0], A1[1], A1[2], A1[3]);
    g4[(256 + r) * 2 + 1] = make_float4(A1[4], A1[5], A1[6], A1[7]);
  }
  __syncthreads();
  for (int idx = tid; idx < 1024; idx += 256) {
    int jj = idx >> 3, tt = idx & 7;
    float gi = glb[jj * 8 + tt]         + bias[jj];
    float gf = glb[(128 + jj) * 8 + tt] + bias[128 + jj];
    float gg = glb[(256 + jj) * 8 + tt] + bias[256 + jj];
    float go = glb[(384 + jj) * 8 + tt] + bias[384 + jj];
    float cold = cL[idx], hold = hL[idx];
    float c2 = sigm(gf) * cold + sigm(gi) * tanh_(gg);
    float h2 = sigm(go) * tanh_(c2);
    float hb = fmaf(alpha, h2 - hold, hold);
    float cb = fmaf(alpha, c2 - cold, cold);
    hL[idx] = hb; cL[idx] = cb;
    if (hout) hout[idx] = hb;
  }
  __syncthreads();
}

// ---------------------------------------------------------------------------
// MEGA kernel: grid 256 blocks x 256 thr. Role = blockIdx%8, idx = blockIdx/8
// (HW round-robins blockIdx%8 over the 8 XCDs):
//   role 0 (idx 0-31): G1 layer0 -- all 32 blocks on XCD 0 => the h0 peer
//     exchange is same-XCD. Wave0 double-publishes h0: tagged copy to
//     h0ringL (XCD0-local peers) + tagged copy to h0ringG (feeds G2).
//   role 1 (idx 0-31): G2 layer1 -- XCD 1; h1 peer exchange via h1ringL
//     (same-XCD); consumes h0ringG with a t+2 prefetch (cross-XCD latency
//     hidden off the critical path).
//   role 2, idx<8 : phaseC per-e output LSTM
//   role >=3      : consumers cid=(role-3)*32+idx < NCON; rest exit.
// Protocol = R7 data-is-flag (3-bit mantissa gen tags, no per-step flags,
// load-once + own-32B retry). If the XCD placement assumption is wrong this
// degrades gracefully to R7 behavior (agent ops are placement-independent).
// ---------------------------------------------------------------------------
__launch_bounds__(256, 1)
__global__ void megaK(const float* __restrict__ feat,
                      const float* __restrict__ pre_h0, const float* __restrict__ pre_c0,
                      const float* __restrict__ wt_p0, const float* __restrict__ wt_p1,
                      const float* __restrict__ b_p0, const float* __restrict__ b_p1,
                      float* __restrict__ h0ringL, float* __restrict__ h0ringG,
                      float* __restrict__ h1ringL,
                      float* __restrict__ h1all, int* __restrict__ flagsBC,
                      const float* __restrict__ Wfc, const float* __restrict__ bfc,
                      const float* __restrict__ wt_c0, const float* __restrict__ wt_c1,
                      const float* __restrict__ b_c0, const float* __restrict__ b_c1,
                      const float* __restrict__ wt_o1, const float* __restrict__ b_o,
                      float* __restrict__ opre1, int* __restrict__ flagC,
                      const __hip_bfloat16* __restrict__ opre2,
                      const float* __restrict__ Whh_o, const float* __restrict__ out_h0,
                      const float* __restrict__ out_c0, float* __restrict__ oh_g) {
  __shared__ float lds[38912];   // 155,648 B
  const int role = blockIdx.x & 7, idx = blockIdx.x >> 3;
  const int tid = threadIdx.x;

  if (role == 0) {
    // ============== G1: layer0 (32 blocks, all on XCD 0) ==============
    const int wg = idx;
    float* wl  = lds;             // 14336: weights [k][32], k<448
    float* xb0 = lds + 14336;     // 1536 (x double buffer A)
    float* xb1 = lds + 15872;     // 1536 (x double buffer B)
    float* hsf = lds + 17408;     // 2048
    float* gl  = lds + 19456;     // 2048 partials
    const int r5 = tid & 31, kq = tid >> 5;
    for (int i2 = tid; i2 < 14336; i2 += 256)
      wl[i2] = wt_p0[(size_t)(i2 >> 5) * 1024 + wg * 32 + (i2 & 31)];
    float creg = 0.f, bi = 0.f, bff = 0.f, bg = 0.f, bo = 0.f;
    if (tid < 64) {
      const int jl = tid >> 3, e = tid & 7, j = wg * 8 + jl;
      creg = pre_c0[(e * 2 + 0) * 256 + j];
      bi = b_p0[j]; bff = b_p0[256 + j]; bg = b_p0[512 + j]; bo = b_p0[768 + j];
    }
    for (int i2 = tid; i2 < 2048; i2 += 256) {
      int k = i2 >> 3, e = i2 & 7;
      hsf[i2] = pre_h0[(e * 2 + 0) * 256 + k];
    }
    for (int i2 = tid; i2 < 1536; i2 += 256) {
      int k = i2 >> 3, e = i2 & 7;
      xb0[i2] = (k < 128) ? feat[k] : feat[128 + e * 64 + (k - 128)];
    }
    __syncthreads();
    const bool own = ((tid >> 3) == wg);
    float Ax[8] = {0,0,0,0,0,0,0,0};
    {
      const float4* x4 = (const float4*)xb0;
      #pragma unroll
      for (int k = kq * 24; k < kq * 24 + 24; ++k) {
        float w = wl[k * 32 + r5];
        float4 a = x4[k * 2], b = x4[k * 2 + 1];
        FMA_8(Ax, w, a, b);
      }
    }
    for (int t = 0; t < T_; ++t) {
      float px[6];
      if (t + 1 < T_) {
        const float* ft1 = feat + (size_t)(t + 1) * 640;
        #pragma unroll
        for (int i = 0; i < 6; ++i) {
          int i2 = tid + i * 256; int k = i2 >> 3, e = i2 & 7;
          px[i] = (k < 128) ? ft1[k] : ft1[128 + e * 64 + (k - 128)];
        }
      }
      float A[8];
      #pragma unroll
      for (int i = 0; i < 8; ++i) A[i] = Ax[i];
      {
        const float4* h4 = (const float4*)hsf;
        #pragma unroll
        for (int k2 = 0; k2 < 32; ++k2) {
          const int k = kq * 32 + k2;
          float w = wl[(192 + k) * 32 + r5];
          float4 a = h4[k * 2], b = h4[k * 2 + 1];
          FMA_8(A, w, a, b);
        }
      }
      {
        float4* g4 = (float4*)gl;
        g4[(kq * 32 + r5) * 2]     = make_float4(A[0], A[1], A[2], A[3]);
        g4[(kq * 32 + r5) * 2 + 1] = make_float4(A[4], A[5], A[6], A[7]);
      }
      if (t + 1 < T_) {                            // stage x(t+1) into alt buffer
        float* xbN = ((t + 1) & 1) ? xb1 : xb0;
        #pragma unroll
        for (int i = 0; i < 6; ++i) xbN[tid + i * 256] = px[i];
      }
      if (t >= 24 && tid >= 224) {                 // back-pressure, lag 24 (8-step gran)
        const int t2 = (t - 24) | 7;
        const int* fp = flagsBC + ((size_t)(t2 & 63) * 32 + (tid - 224)) * 32;
        while (aload32(fp) < t2 + 1) __builtin_amdgcn_s_sleep(16);
      }
      lbar();                                      // S1
      const unsigned g = ((unsigned)(t >> 5) % 7u) + 1u;
      float* ringS = h0ringL + (size_t)(t & 31) * 2048;
      if (tid < 64) {
        float s0 = 0.f, s1 = 0.f, s2 = 0.f, s3 = 0.f;
        #pragma unroll
        for (int q = 0; q < 8; ++q) {
          s0 += gl[q * 256 + tid];       s1 += gl[q * 256 + 64 + tid];
          s2 += gl[q * 256 + 128 + tid]; s3 += gl[q * 256 + 192 + tid];
        }
        float c2 = sigm(s1 + bff) * creg + sigm(s0 + bi) * tanh_(s2 + bg);
        float h2 = sigm(s3 + bo) * tanh_(c2);
        creg = c2;
        float tv = tagf(h2, g);
        __hip_atomic_store(&ringS[wg * 64 + tid], tv,
                           __ATOMIC_RELAXED, __HIP_MEMORY_SCOPE_AGENT);
        __hip_atomic_store(&h0ringG[(size_t)(t & 31) * 2048 + wg * 64 + tid], tv,
                           __ATOMIC_RELAXED, __HIP_MEMORY_SCOPE_AGENT);
        hsf[wg * 64 + tid] = h2;                   // own slice direct to LDS
      }
      if (t + 1 >= T_) break;
      ull v[4];
      const ull* rp = (const ull*)ringS + tid * 4;
      if (!own) {
        #pragma unroll
        for (int i = 0; i < 4; ++i) v[i] = aload64(rp + i);  // in flight
      }
      #pragma unroll
      for (int i = 0; i < 8; ++i) Ax[i] = 0.f;
      {                                            // x-matvec hides data flight
        const float4* x4 = (const float4*)(((t + 1) & 1) ? xb1 : xb0);
        #pragma unroll
        for (int k = kq * 24; k < kq * 24 + 24; ++k) {
          float w = wl[k * 32 + r5];
          float4 a = x4[k * 2], b = x4[k * 2 + 1];
          FMA_8(Ax, w, a, b);
        }
      }
      if (!own) {
        while (!tagok4(v, g)) {                    // retry own 32 B only
          __builtin_amdgcn_s_sleep(1);
          #pragma unroll
          for (int i = 0; i < 4; ++i) v[i] = aload64(rp + i);
        }
        ull* d8 = (ull*)hsf;
        #pragma unroll
        for (int i = 0; i < 4; ++i) d8[tid * 4 + i] = v[i];
      }
      lbar();                                      // S4
    }
  } else if (role == 1) {
    // ============== G2: layer1 (32 blocks, all on XCD 1) ==============
    const int wgl = idx;
    float* wl  = lds;             // 16384: weights [k][32], k<512
    float* xh0 = lds + 16384;     // 2048
    float* hsf = lds + 18432;     // 2048
    float* gl  = lds + 20480;     // 2048
    const int r5 = tid & 31, kq = tid >> 5;
    for (int i2 = tid; i2 < 16384; i2 += 256)
      wl[i2] = wt_p1[(size_t)(i2 >> 5) * 1024 + wgl * 32 + (i2 & 31)];
    float creg = 0.f, bi = 0.f, bff = 0.f, bg = 0.f, bo = 0.f;
    if (tid < 64) {
      const int jl = tid >> 3, e = tid & 7, j = wgl * 8 + jl;
      creg = pre_c0[(e * 2 + 1) * 256 + j];
      bi = b_p1[j]; bff = b_p1[256 + j]; bg = b_p1[512 + j]; bo = b_p1[768 + j];
    }
    for (int i2 = tid; i2 < 2048; i2 += 256) {
      int k = i2 >> 3, e = i2 & 7;
      hsf[i2] = pre_h0[(e * 2 + 1) * 256 + k];
    }
    __syncthreads();
    const bool own = ((tid >> 3) == wgl);
    ull pv[4];
    {                                              // prologue: h0(0) -> xh0 (gen 1)
      ull v[4];
      const ull* rp = (const ull*)h0ringG + tid * 4;
      #pragma unroll
      for (int i = 0; i < 4; ++i) v[i] = aload64(rp + i);
      while (!tagok4(v, 1u)) {
        __builtin_amdgcn_s_sleep(1);
        #pragma unroll
        for (int i = 0; i < 4; ++i) v[i] = aload64(rp + i);
      }
      ull* d8 = (ull*)xh0;
      #pragma unroll
      for (int i = 0; i < 4; ++i) d8[tid * 4 + i] = v[i];
    }
    lbar();
    float Ax[8] = {0,0,0,0,0,0,0,0};
    {
      const float4* x4 = (const float4*)xh0;
      #pragma unroll
      for (int k = kq * 32; k < kq * 32 + 32; ++k) {
        float w = wl[k * 32 + r5];
        float4 a = x4[k * 2], b = x4[k * 2 + 1];
        FMA_8(Ax, w, a, b);
      }
    }
    {                                              // prologue: h0(1) -> pv (gen 1)
      const ull* rp = (const ull*)(h0ringG + 2048) + tid * 4;
      #pragma unroll
      for (int i = 0; i < 4; ++i) pv[i] = aload64(rp + i);
      while (!tagok4(pv, 1u)) {
        __builtin_amdgcn_s_sleep(1);
        #pragma unroll
        for (int i = 0; i < 4; ++i) pv[i] = aload64(rp + i);
      }
    }
    lbar();                                        // xh0 reads done before t=0 stage
    for (int t = 0; t < T_; ++t) {
      float A[8];
      #pragma unroll
      for (int i = 0; i < 8; ++i) A[i] = Ax[i];
      {
        const float4* h4 = (const float4*)hsf;
        #pragma unroll
        for (int k2 = 0; k2 < 32; ++k2) {
          const int k = kq * 32 + k2;
          float w = wl[(256 + k) * 32 + r5];
          float4 a = h4[k * 2], b = h4[k * 2 + 1];
          FMA_8(A, w, a, b);
        }
      }
      {
        float4* g4 = (float4*)gl;
        g4[(kq * 32 + r5) * 2]     = make_float4(A[0], A[1], A[2], A[3]);
        g4[(kq * 32 + r5) * 2 + 1] = make_float4(A[4], A[5], A[6], A[7]);
      }
      if (t + 1 < T_) {                            // stage xh0 = h0(t+1) from pv
        ull* d8 = (ull*)xh0;
        #pragma unroll
        for (int i = 0; i < 4; ++i) d8[tid * 4 + i] = pv[i];
      }
      lbar();                                      // S1
      const unsigned g1 = ((unsigned)(t >> 3) % 7u) + 1u;
      float* ringS = h1ringL + (size_t)(t & 7) * 2048;
      if (tid < 64) {
        float s0 = 0.f, s1 = 0.f, s2 = 0.f, s3 = 0.f;
        #pragma unroll
        for (int q = 0; q < 8; ++q) {
          s0 += gl[q * 256 + tid];       s1 += gl[q * 256 + 64 + tid];
          s2 += gl[q * 256 + 128 + tid]; s3 += gl[q * 256 + 192 + tid];
        }
        float c2 = sigm(s1 + bff) * creg + sigm(s0 + bi) * tanh_(s2 + bg);
        float h2 = sigm(s3 + bo) * tanh_(c2);
        creg = c2;
        __hip_atomic_store(&ringS[wgl * 64 + tid], tagf(h2, g1),
                           __ATOMIC_RELAXED, __HIP_MEMORY_SCOPE_AGENT);
        hsf[wgl * 64 + tid] = h2;                  // own slice direct to LDS
        __hip_atomic_store(&h1all[(size_t)t * 2048 + wgl * 64 + tid], h2,
                           __ATOMIC_RELAXED, __HIP_MEMORY_SCOPE_AGENT);
        if ((t & 7) == 7) {                        // acked consumer-facing flag
          asm volatile("s_waitcnt vmcnt(0)" ::: "memory");  // drains h1all
          if (tid == 0)
            __hip_atomic_store(&flagsBC[((size_t)(t & 63) * 32 + wgl) * 32], t + 1,
                               __ATOMIC_RELAXED, __HIP_MEMORY_SCOPE_AGENT);
        }
      }
      if (t + 1 >= T_) break;
      ull w1[4];
      const ull* rp1 = (const ull*)ringS + tid * 4;
      if (!own) {
        #pragma unroll
        for (int i = 0; i < 4; ++i) w1[i] = aload64(rp1 + i);  // in flight
      }
      #pragma unroll
      for (int i = 0; i < 8; ++i) Ax[i] = 0.f;
      {                                            // x-matvec hides data flight
        const float4* x4 = (const float4*)xh0;
        #pragma unroll
        for (int k = kq * 32; k < kq * 32 + 32; ++k) {
          float w = wl[k * 32 + r5];
          float4 a = x4[k * 2], b = x4[k * 2 + 1];
          FMA_8(Ax, w, a, b);
        }
      }
      if (!own) {
        while (!tagok4(w1, g1)) {
          __builtin_amdgcn_s_sleep(1);
          #pragma unroll
          for (int i = 0; i < 4; ++i) w1[i] = aload64(rp1 + i);
        }
        ull* d8 = (ull*)hsf;
        #pragma unroll
        for (int i = 0; i < 4; ++i) d8[tid * 4 + i] = w1[i];
      }
      if (t + 2 < T_) {                            // prefetch h0(t+2): G1 runs ahead
        const unsigned g0 = ((unsigned)((t + 2) >> 5) % 7u) + 1u;
        const ull* rp0 = (const ull*)(h0ringG + (size_t)((t + 2) & 31) * 2048) + tid * 4;
        #pragma unroll
        for (int i = 0; i < 4; ++i) pv[i] = aload64(rp0 + i);
        while (!tagok4(pv, g0)) {                  // rare spin (backpressure margin)
          __builtin_amdgcn_s_sleep(1);
          #pragma unroll
          for (int i = 0; i < 4; ++i) pv[i] = aload64(rp0 + i);
        }
      }
      lbar();                                      // S4
    }
  } else if (role == 2 && idx < 8) {
    // ============================ phaseC (per e) ============================
    const int e = idx;
    float* wlds = lds;            // [k][256] rows 256-511: 32768 floats
    float* ohl  = lds + 32768;    // 128
    float* gl   = lds + 32896;    // 512
    for (int i2 = tid; i2 < 32768; i2 += 256) {
      int k = i2 >> 8, rr = i2 & 255;
      wlds[i2] = Whh_o[(256 + rr) * 128 + k];
    }
    float w[128];
    #pragma unroll
    for (int k = 0; k < 128; ++k) w[k] = Whh_o[tid * 128 + k];
    if (tid < 128) ohl[tid] = out_h0[e * 128 + tid];
    float creg = (tid < 128) ? out_c0[e * 128 + tid] : 0.f;
    __syncthreads();
    if (tid == 0) { while (aload32(&flagC[0]) == 0) __builtin_amdgcn_s_sleep(4); }
    __syncthreads();
    const int r0 = tid, r1 = tid + 256;
    float pa = aloadf(&opre1[r0]), pb = aloadf(&opre1[r1]);
    float qa = __bfloat162float(opre2[(size_t)e * 512 + r0]);
    float qb = __bfloat162float(opre2[(size_t)e * 512 + r1]);
    float na = aloadf(&opre1[512 + r0]), nb = aloadf(&opre1[512 + r1]);
    float ma = __bfloat162float(opre2[(size_t)(8 + e) * 512 + r0]);
    float mb = __bfloat162float(opre2[(size_t)(8 + e) * 512 + r1]);
    for (int t = 0; t < T_; ++t) {
      float a0 = pa + qa, a1 = pb + qb;
      pa = na; pb = nb; qa = ma; qb = mb;
      if ((t & 7) == 6 && t + 2 < T_) {            // next chunk ready?
        if (tid == 0) { while (aload32(&flagC[((t + 2) >> 3) * 32]) == 0) __builtin_amdgcn_s_sleep(4); }
        __syncthreads();
      }
      if (t + 2 < T_) {
        na = aloadf(&opre1[(size_t)(t + 2) * 512 + r0]);
        nb = aloadf(&opre1[(size_t)(t + 2) * 512 + r1]);
        ma = __bfloat162float(opre2[((size_t)(t + 2) * 8 + e) * 512 + r0]);
        mb = __bfloat162float(opre2[((size_t)(t + 2) * 8 + e) * 512 + r1]);
      }
      const float4* o4 = (const float4*)ohl;
      #pragma unroll
      for (int kk = 0; kk < 32; ++kk) {
        float4 x = o4[kk];
        a0 = fmaf(w[kk * 4 + 0], x.x, a0); a0 = fmaf(w[kk * 4 + 1], x.y, a0);
        a0 = fmaf(w[kk * 4 + 2], x.z, a0); a0 = fmaf(w[kk * 4 + 3], x.w, a0);
        a1 = fmaf(wlds[(kk * 4 + 0) * 256 + tid], x.x, a1);
        a1 = fmaf(wlds[(kk * 4 + 1) * 256 + tid], x.y, a1);
        a1 = fmaf(wlds[(kk * 4 + 2) * 256 + tid], x.z, a1);
        a1 = fmaf(wlds[(kk * 4 + 3) * 256 + tid], x.w, a1);
      }
      gl[r0] = a0; gl[r1] = a1;
      __syncthreads();
      if (tid < 128) {
        float gi = gl[tid], gf = gl[128 + tid], gg = gl[256 + tid], go = gl[384 + tid];
        float c2 = sigm(gf) * creg + sigm(gi) * tanh_(gg);
        float h2 = sigm(go) * tanh_(c2);
        creg = c2;
        ohl[tid] = h2;
        oh_g[(size_t)t * 1024 + e * 128 + tid] = h2;
      }
      __syncthreads();
    }
  } else if (role >= 3) {
    // ==================== consumers: fused fc + comm ====================
    const int cb = (role - 3) * 32 + idx;
    if (cb >= NCON) return;
    float* h1c    = lds;          // 16384
    float* polAll = lds + 16384;  // 8192
    float* ch0 = lds + 24576; float* cc0 = lds + 25600;
    float* ch1 = lds + 26624; float* cc1 = lds + 27648;
    float* h0b = lds + 28672;     // 1024
    float* glb = lds + 29696;     // 4096
    for (int chunk = cb; chunk < 512; chunk += NCON) {
      const int t0 = chunk * 8;
      if (tid < 32) {
        const int* fp = flagsBC + ((size_t)((t0 + 7) & 63) * 32 + tid) * 32;
        while (aload32(fp) < t0 + 8) __builtin_amdgcn_s_sleep(64);
      }
      __syncthreads();
      {
        const ull* src = (const ull*)(h1all + (size_t)t0 * 2048);
        ull* dst = (ull*)h1c;
        for (int i = tid; i < 8192; i += 256) dst[i] = aload64(src + i);
      }
      __syncthreads();
      {  // fc for 8 ts -> polAll[e][c*8+tt]
        const int c = tid >> 1, half = tid & 1;
        const float bv = bfc[c];
        const float* wrow = Wfc + c * 256;
        for (int tt = 0; tt < 8; ++tt) {
          float a0 = bv, a1 = bv, a2 = bv, a3 = bv;
          const float4* h4 = (const float4*)(h1c + tt * 2048);
          #pragma unroll 4
          for (int k = 0; k < 256; ++k) {
            float wv = wrow[k];
            float4 x = h4[k * 2 + half];
            a0 = fmaf(wv, x.x, a0); a1 = fmaf(wv, x.y, a1);
            a2 = fmaf(wv, x.z, a2); a3 = fmaf(wv, x.w, a3);
          }
          float vv[4] = {a0, a1, a2, a3};
          #pragma unroll
          for (int i = 0; i < 4; ++i) {
            float v = vv[i];
            v = (v > 0.f) ? v : 0.05f * v;
            polAll[(half * 4 + i) * 1024 + c * 8 + tt] = v;
          }
        }
      }
      for (int i2 = tid; i2 < 1024; i2 += 256) { ch0[i2]=0.f; cc0[i2]=0.f; ch1[i2]=0.f; cc1[i2]=0.f; }
      __syncthreads();
      float alpha = 1.0f;
      for (int rd = 0; rd < 3; ++rd) {
        for (int e = 0; e < E_; ++e) {
          comm_cell(wt_c0, b_c0, polAll + e * 1024, ch0, cc0, glb, h0b, alpha, tid);
          comm_cell(wt_c1, b_c1, h0b, ch1, cc1, glb, nullptr, alpha, tid);
        }
        alpha *= 0.333f;
      }
      {  // opre1 epilogue (atomic stores for intra-kernel visibility)
        const int r = tid;
        float A0[8], A1[8];
        #pragma unroll
        for (int tt = 0; tt < 8; ++tt) { A0[tt] = b_o[r]; A1[tt] = b_o[256 + r]; }
        const float4* c04 = (const float4*)cc0;
        const float4* c14 = (const float4*)cc1;
        #pragma unroll 2
        for (int k = 0; k < 128; ++k) {
          float w0 = wt_o1[k * 512 + r], w1 = wt_o1[k * 512 + 256 + r];
          float4 a = c04[k * 2], b = c04[k * 2 + 1];
          FMA_8(A0, w0, a, b);
          FMA_8(A1, w1, a, b);
        }
        #pragma unroll 2
        for (int k = 0; k < 128; ++k) {
          float w0 = wt_o1[(128 + k) * 512 + r], w1 = wt_o1[(128 + k) * 512 + 256 + r];
          float4 a = c14[k * 2], b = c14[k * 2 + 1];
          FMA_8(A0, w0, a, b);
          FMA_8(A1, w1, a, b);
        }
        #pragma unroll
        for (int tt = 0; tt < 8; ++tt) {
          __hip_atomic_store(&opre1[((size_t)(t0 + tt)) * 512 + r], A0[tt],
                             __ATOMIC_RELAXED, __HIP_MEMORY_SCOPE_AGENT);
          __hip_atomic_store(&opre1[((size_t)(t0 + tt)) * 512 + 256 + r], A1[tt],
                             __ATOMIC_RELAXED, __HIP_MEMORY_SCOPE_AGENT);
        }
      }
      __syncthreads();                             // drain opre1 (vmcnt0)
      if (tid == 0)
        __hip_atomic_store(&flagC[chunk * 32], 1, __ATOMIC_RELAXED, __HIP_MEMORY_SCOPE_AGENT);
      __syncthreads();
    }
  }
}

// ---------------------------------------------------------------------------
// phaseD: parallel over t: softmaxes
// ---------------------------------------------------------------------------
__global__ void phaseD(const float* __restrict__ oh_g,
                       const float* __restrict__ Wtar, const float* __restrict__ btar,
                       const float* __restrict__ Wdir, const float* __restrict__ bdir,
                       float* __restrict__ outp) {
  __shared__ float ohl[1024];
  const int t = blockIdx.x, tid = threadIdx.x;  // 64 threads
  for (int idx = tid; idx < 1024; idx += 64) ohl[idx] = oh_g[(size_t)t * 1024 + idx];
  __syncthreads();
  const int f = tid;
  for (int e = 0; e < E_; ++e) {
    float acc = btar[f];
    const float* wr = Wtar + f * 128;
    #pragma unroll 4
    for (int k = 0; k < 128; ++k) acc = fmaf(wr[k], ohl[e * 128 + k], acc);
    float m = acc;
    #pragma unroll
    for (int off = 32; off; off >>= 1) m = fmaxf(m, __shfl_xor(m, off, 64));
    float ex = __expf(acc - m);
    float s = ex;
    #pragma unroll
    for (int off = 32; off; off >>= 1) s += __shfl_xor(s, off, 64);
    outp[((size_t)t * 8 + e) * 64 + f] = ex / s;
  }
  if (tid < 8) {
    int e = tid;
    float d0 = bdir[0], d1 = bdir[1], d2 = bdir[2];
    #pragma unroll 4
    for (int k = 0; k < 128; ++k) {
      float x = ohl[e * 128 + k];
      d0 = fmaf(Wdir[k], x, d0);
      d1 = fmaf(Wdir[128 + k], x, d1);
      d2 = fmaf(Wdir[256 + k], x, d2);
    }
    float m = fmaxf(d0, fmaxf(d1, d2));
    float x0 = __expf(d0 - m), x1 = __expf(d1 - m), x2 = __expf(d2 - m);
    float s = x0 + x1 + x2;
    float* dp = outp + (size_t)T_ * 8 * 64 + ((size_t)t * 8 + e) * 3;
    dp[0] = x0 / s; dp[1] = x1 / s; dp[2] = x2 / s;
  }
}

extern "C" void kernel_launch(void* const* d_in, const int* in_sizes, int n_in,
                              void* d_out, int out_size, void* d_ws, size_t ws_size,
                              hipStream_t stream) {
  (void)in_sizes; (void)n_in; (void)out_size; (void)ws_size;
  const float* feat   = (const float*)d_in[0];
  const float* pre_h0 = (const float*)d_in[1];
  const float* pre_c0 = (const float*)d_in[2];
  const float* out_h0 = (const float*)d_in[3];
  const float* out_c0 = (const float*)d_in[4];
  const float* Wih_p0 = (const float*)d_in[5];
  const float* Whh_p0 = (const float*)d_in[6];
  const float* b_p0   = (const float*)d_in[7];
  const float* Wih_p1 = (const float*)d_in[8];
  const float* Whh_p1 = (const float*)d_in[9];
  const float* b_p1   = (const float*)d_in[10];
  const float* Wfc    = (const float*)d_in[11];
  const float* bfc    = (const float*)d_in[12];
  const float* Wih_c0 = (const float*)d_in[13];
  const float* Whh_c0 = (const float*)d_in[14];
  const float* b_c0   = (const float*)d_in[15];
  const float* Wih_c1 = (const float*)d_in[16];
  const float* Whh_c1 = (const float*)d_in[17];
  const float* b_c1   = (const float*)d_in[18];
  const float* Wih_o  = (const float*)d_in[19];
  const float* Whh_o  = (const float*)d_in[20];
  const float* b_o    = (const float*)d_in[21];
  const float* Wtar   = (const float*)d_in[22];
  const float* btar   = (const float*)d_in[23];
  const float* Wdir   = (const float*)d_in[24];
  const float* bdir   = (const float*)d_in[25];
  float* outp = (float*)d_out;

  float* ws = (float*)d_ws;
  size_t off = 0;
  float* opre1    = ws + off; off += (size_t)T_ * 512;
  float* oh_g     = ws + off; off += (size_t)T_ * E_ * 128;
  float* wt_p0    = ws + off; off += (size_t)448 * 1024;
  float* wt_p1    = ws + off; off += (size_t)512 * 1024;
  float* wt_c0    = ws + off; off += (size_t)256 * 512;
  float* wt_c1    = ws + off; off += (size_t)256 * 512;
  float* wt_o1    = ws + off; off += (size_t)256 * 512;
  float* wt_o2    = ws + off; off += (size_t)192 * 512;
  __hip_bfloat16* opre2 = (__hip_bfloat16*)(ws + off);
  off += (size_t)T_ * E_ * 512 / 2;
  float* h1all   = ws + off; off += (size_t)T_ * 2048;
  float* h0ringL = ws + off; off += (size_t)32 * 2048;  // G1-peer ring (XCD0)
  float* h0ringG = ws + off; off += (size_t)32 * 2048;  // G1->G2 feed ring
  float* h1ringL = ws + off; off += (size_t)8 * 2048;   // G2-peer ring (XCD1)
  int* flags    = (int*)(ws + off);
  int* flagsBC  = flags;                                 // 64*32*32 (8-step, acked)
  int* flagC    = flags + (size_t)64 * 32 * 32;          // 512*32
  int* zbase    = (int*)h0ringL;  // zero span: rings + flags

  initK<<<dim3(1024), dim3(256), 0, stream>>>(
      Wih_p0, Whh_p0, Wih_p1, Whh_p1, Wih_c0, Whh_c0, Wih_c1, Whh_c1, Wih_o,
      wt_p0, wt_p1, wt_c0, wt_c1, wt_o1, wt_o2, zbase);
  opre2K<<<dim3(T_), dim3(256), 0, stream>>>(feat, wt_o2, opre2);
  megaK<<<dim3(256), dim3(256), 0, stream>>>(
      feat, pre_h0, pre_c0, wt_p0, wt_p1, b_p0, b_p1,
      h0ringL, h0ringG, h1ringL, h1all, flagsBC,
      Wfc, bfc, wt_c0, wt_c1, b_c0, b_c1, wt_o1, b_o, opre1, flagC,
      opre2, Whh_o, out_h0, out_c0, oh_g);
  phaseD<<<dim3(T_), dim3(64), 0, stream>>>(oh_g, Wtar, btar, Wdir, bdir, outp);
}